// Round 5
// baseline (555.614 us; speedup 1.0000x reference)
//
#include <hip/hip_runtime.h>

// ShootingBlockMNModel1 — single fused kernel, regular launch (graph-safe).
// Grid reduction via agent-scope fp32 atomicAdd into gsum[k][36] (no partial
// array, no gather); arrival via one release counter. Block 0 computes the
// theta update and writes each block a PRIVATE 256B slot {sums[36], theta[12],
// flag} — readers poll their own line (zero MALL same-line contention).
// Backfold redundant per block from LDS; final pass fused; q/p pinned in
// VGPRs (loaded once).
//
// ws: gsum[21][64] f32 ; cnt[32] u32 ; slots[256][64] f32  (memset 0, 71040B)

#define LR 0.25f
#define NIT 20
#define TPB 512
#define NB  256

typedef float v2f __attribute__((ext_vector_type(2)));

#define AG_LDF(p)    __hip_atomic_load((p),  __ATOMIC_RELAXED, __HIP_MEMORY_SCOPE_AGENT)
#define AG_LDU(p)    __hip_atomic_load((p),  __ATOMIC_RELAXED, __HIP_MEMORY_SCOPE_AGENT)
#define AG_ADDF(p,v) __hip_atomic_fetch_add((p), (v), __ATOMIC_RELAXED, __HIP_MEMORY_SCOPE_AGENT)

__device__ __forceinline__ void st64_ag(float* p, float a, float b){
    union{ float f[2]; unsigned long long u; } x;
    x.f[0]=a; x.f[1]=b;
    __hip_atomic_store((unsigned long long*)p, x.u,
                       __ATOMIC_RELAXED, __HIP_MEMORY_SCOPE_AGENT);
}

__device__ __forceinline__ v2f tanh2(v2f x){
    v2f e;
    e.x = __expf(x.x + x.x);
    e.y = __expf(x.y + x.y);
    v2f d = e + 1.0f;
    v2f r;
    r.x = __builtin_amdgcn_rcpf(d.x);
    r.y = __builtin_amdgcn_rcpf(d.y);
    return 1.0f - (r + r);
}

// wave64 sum via DPP on the VALU pipe; result valid in lane 63
#define DPP_ADD(x, ctrl) ((x) + __int_as_float(__builtin_amdgcn_update_dpp(0, __float_as_int(x), (ctrl), 0xF, 0xF, true)))
__device__ __forceinline__ float wave_sum64(float x){
    x = DPP_ADD(x, 0x111);   // row_shr:1
    x = DPP_ADD(x, 0x112);   // row_shr:2
    x = DPP_ADD(x, 0x114);   // row_shr:4
    x = DPP_ADD(x, 0x118);   // row_shr:8  -> lane 15+16r = row sum
    x = DPP_ADD(x, 0x142);   // row_bcast:15
    x = DPP_ADD(x, 0x143);   // row_bcast:31 -> lane 63 = total
    return x;
}

__device__ __forceinline__ void compute_grad(const float* s, const float* th,
                                             const float* ksym, const float* ksymb,
                                             float c, float* g){
    const float Ivec[4]={1.f,0.f,0.f,1.f};
    #pragma unroll
    for(int j=0;j<4;j++){
        float kv=0.f;
        #pragma unroll
        for(int m=0;m<4;m++) kv += ksym[j*4+m]*th[m];
        g[j] = kv - c*s[j];
    }
    #pragma unroll
    for(int i2=0;i2<2;i2++)
        g[4+i2] = ksymb[i2*2+0]*th[4] + ksymb[i2*2+1]*th[5] - c*s[4+i2];
    #pragma unroll
    for(int j=0;j<4;j++){
        float kv=0.f;
        #pragma unroll
        for(int m=0;m<4;m++) kv += ksym[j*4+m]*(th[6+m]-Ivec[m]);
        g[6+j] = kv - c*s[6+j];
    }
    #pragma unroll
    for(int i2=0;i2<2;i2++)
        g[10+i2] = ksymb[i2*2+0]*th[10] + ksymb[i2*2+1]*th[11] - c*s[10+i2];
}

// packed accumulate: float4 = 2 samples in v2f lanes
__device__ __forceinline__ void accum_sample2(v2f Q0, v2f Q1, v2f P0, v2f P1,
    float t1_00,float t1_01,float t1_10,float t1_11,
    float t2_00,float t2_01,float t2_10,float t2_11,float b2_0,float b2_1,
    v2f (&acc)[36]){
    v2f u0 = t2_00*Q0 + t2_01*Q1 + b2_0;
    v2f u1 = t2_10*Q0 + t2_11*Q1 + b2_1;
    v2f h0 = tanh2(u0), h1 = tanh2(u1);
    v2f s0 = 1.0f - h0*h0, s1 = 1.0f - h1*h1;
    v2f a0 = t1_00*P0 + t1_10*P1;
    v2f a1 = t1_01*P0 + t1_11*P1;
    v2f w0 = a0*s0, w1 = a1*s1;
    v2f r0 = -2.0f*(a0*h0)*s0, r1 = -2.0f*(a1*h1)*s1;
    acc[0]+=P0*h0; acc[1]+=P0*h1; acc[2]+=P1*h0; acc[3]+=P1*h1;
    acc[4]+=P0;    acc[5]+=P1;
    acc[6]+=w0*Q0; acc[7]+=w0*Q1; acc[8]+=w1*Q0; acc[9]+=w1*Q1;
    acc[10]+=w0;   acc[11]+=w1;
    v2f ps00=P0*s0, ps01=P0*s1, ps10=P1*s0, ps11=P1*s1;
    acc[12]+=ps00*Q0; acc[13]+=ps00*Q1; acc[14]+=ps01*Q0; acc[15]+=ps01*Q1;
    acc[16]+=ps10*Q0; acc[17]+=ps10*Q1; acc[18]+=ps11*Q0; acc[19]+=ps11*Q1;
    acc[20]+=ps00; acc[21]+=ps01; acc[22]+=ps10; acc[23]+=ps11;
    v2f r0q0=r0*Q0, r1q0=r1*Q0;
    acc[24]+=r0q0*Q0; acc[25]+=r0q0*Q1; acc[26]+=r0*(Q1*Q1);
    acc[27]+=r1q0*Q0; acc[28]+=r1q0*Q1; acc[29]+=r1*(Q1*Q1);
    acc[30]+=r0q0; acc[31]+=r0*Q1; acc[32]+=r1q0; acc[33]+=r1*Q1;
    acc[34]+=r0; acc[35]+=r1;
}

__device__ __forceinline__ void bk_step2(v2f Q0, v2f Q1, v2f P0, v2f P1,
    float t1_00,float t1_01,float t1_10,float t1_11,
    float t2_00,float t2_01,float t2_10,float t2_11,float b2_0,float b2_1,
    float L1_00,float L1_01,float L1_10,float L1_11,
    float L2_00,float L2_01,float L2_10,float L2_11,float lb2_0,float lb2_1,
    v2f &B0, v2f &B1){
    v2f u0 = t2_00*Q0 + t2_01*Q1 + b2_0;
    v2f u1 = t2_10*Q0 + t2_11*Q1 + b2_1;
    v2f h0 = tanh2(u0), h1 = tanh2(u1);
    v2f s0 = 1.0f - h0*h0, s1 = 1.0f - h1*h1;
    v2f a0 = t1_00*P0 + t1_10*P1;
    v2f a1 = t1_01*P0 + t1_11*P1;
    v2f w0 = a0*s0, w1 = a1*s1;
    v2f r0 = -2.0f*(a0*h0)*s0, r1 = -2.0f*(a1*h1)*s1;
    v2f lp0 = L1_00*P0 + L1_10*P1;
    v2f lp1 = L1_01*P0 + L1_11*P1;
    v2f z0 = L2_00*Q0 + L2_01*Q1 + lb2_0;
    v2f z1 = L2_10*Q0 + L2_11*Q1 + lb2_1;
    v2f m0 = lp0*s0 + r0*z0;
    v2f m1 = lp1*s1 + r1*z1;
    B0 += t2_00*m0 + t2_10*m1 + L2_00*w0 + L2_10*w1;
    B1 += t2_01*m0 + t2_11*m1 + L2_01*w0 + L2_11*w1;
}

__global__ __launch_bounds__(TPB, 2) void k_all(
    const float4* __restrict__ q4, const float4* __restrict__ p4,
    const float4* __restrict__ x4, int nv4,
    const float* __restrict__ t1i, const float* __restrict__ b1i,
    const float* __restrict__ t2i, const float* __restrict__ b2i,
    const float* __restrict__ invK, const float* __restrict__ invKb,
    float* __restrict__ gsum,            // [NIT+1][64], zeroed
    unsigned* __restrict__ cnt,          // [32], zeroed
    float* __restrict__ slots,           // [NB][64], zeroed (flag dwords)
    float4* __restrict__ oq, float4* __restrict__ op, float4* __restrict__ ox,
    float c)
{
    const int tid  = threadIdx.x;
    const int bid  = blockIdx.x;
    const int NT   = gridDim.x * TPB;
    const int gtid = bid*TPB + tid;
    const int wave = tid >> 6, lane = tid & 63;

    __shared__ float ths[12];                  // current theta
    __shared__ float thetaAll[(NIT+1)*12];     // theta stash (all iterations)
    __shared__ float sAll[(NIT+1)*36];         // sums stash (all iterations)
    __shared__ float red[TPB/64][36];
    __shared__ float ks[16], ksb[4];
    __shared__ float4 pkS[NIT*5];              // packed theta_k + lam_{k+1}

    if(tid < 16) ks[tid]  = 0.5f*(invK[tid]  + invK[(tid&3)*4 + (tid>>2)]);
    if(tid < 4)  ksb[tid] = 0.5f*(invKb[tid] + invKb[(tid&1)*2 + (tid>>1)]);
    if(tid < 12){
        float v = (tid<4)? t1i[tid] : (tid<6)? b1i[tid-4]
                : (tid<10)? t2i[tid-6] : b2i[tid-10];
        ths[tid] = v;
        thetaAll[tid] = v;
    }
    __syncthreads();

    // Pin this thread's samples in registers for the whole kernel.
    const bool fast = (nv4 == 4*NT);
    float4 qd[4], pd[4];
    if(fast){
        #pragma unroll
        for(int sl=0; sl<4; sl++){ qd[sl]=q4[gtid + sl*NT]; pd[sl]=p4[gtid + sl*NT]; }
    }

    for(int k=0; k<=NIT; k++){
        const float t1_00=ths[0], t1_01=ths[1], t1_10=ths[2], t1_11=ths[3];
        const float t2_00=ths[6], t2_01=ths[7], t2_10=ths[8], t2_11=ths[9];
        const float b2_0=ths[10], b2_1=ths[11];

        v2f acc[36];
        #pragma unroll
        for(int j=0;j<36;j++) acc[j] = (v2f){0.f, 0.f};

        if(fast){
            #pragma unroll
            for(int sl=0; sl<4; sl++){
                v2f Q0={qd[sl].x,qd[sl].z}, Q1={qd[sl].y,qd[sl].w};
                v2f P0={pd[sl].x,pd[sl].z}, P1={pd[sl].y,pd[sl].w};
                accum_sample2(Q0,Q1,P0,P1,
                    t1_00,t1_01,t1_10,t1_11,t2_00,t2_01,t2_10,t2_11,b2_0,b2_1,acc);
            }
        }else{
            for(int j = gtid; j < nv4; j += NT){
                float4 qq = q4[j], pp = p4[j];
                v2f Q0={qq.x,qq.z}, Q1={qq.y,qq.w};
                v2f P0={pp.x,pp.z}, P1={pp.y,pp.w};
                accum_sample2(Q0,Q1,P0,P1,
                    t1_00,t1_01,t1_10,t1_11,t2_00,t2_01,t2_10,t2_11,b2_0,b2_1,acc);
            }
        }

        // wave reduction (VALU pipe) -> block partial -> global atomicAdd
        float wres[36];
        #pragma unroll
        for(int j=0;j<36;j++) wres[j] = wave_sum64(acc[j].x + acc[j].y);
        if(lane == 63){
            #pragma unroll
            for(int j=0;j<36;j++) red[wave][j] = wres[j];
        }
        __syncthreads();
        if(tid < 36){
            float sum = 0.f;
            #pragma unroll
            for(int w=0; w<TPB/64; w++) sum += red[w][tid];
            AG_ADDF(gsum + k*64 + tid, sum);
        }
        // arrival: same wave (0) as the adds — release waits that wave's vmcnt
        if(tid == 0)
            __hip_atomic_fetch_add(cnt + k, 1u,
                                   __ATOMIC_RELEASE, __HIP_MEMORY_SCOPE_AGENT);

        if(bid == 0){
            if(wave == 0){
                int guard = 0;
                for(;;){
                    unsigned v = AG_LDU(cnt + k);
                    if(v >= (unsigned)NB) break;
                    __builtin_amdgcn_s_sleep(1);
                    if(++guard > (1<<17)) break;   // watchdog: never hang
                }
                if(lane < 36) sAll[k*36 + lane] = AG_LDF(gsum + k*64 + lane);
            }
            __syncthreads();
            if(tid == 0 && k < NIT){
                float g[12];
                compute_grad(sAll + k*36, thetaAll + k*12, ks, ksb, c, g);
                #pragma unroll
                for(int j=0;j<12;j++){
                    float t = thetaAll[k*12+j] - LR*g[j];
                    ths[j] = t;
                    thetaAll[(k+1)*12+j] = t;
                }
            }
            __syncthreads();
            // write every reader's PRIVATE slot {sums, theta_next, flag}
            if(tid < NB){
                float* sp = slots + tid*64;
                #pragma unroll
                for(int i=0;i<18;i++)
                    st64_ag(sp + 2*i, sAll[k*36 + 2*i], sAll[k*36 + 2*i + 1]);
                if(k < NIT){
                    #pragma unroll
                    for(int i=0;i<6;i++)
                        st64_ag(sp + 36 + 2*i,
                                thetaAll[(k+1)*12 + 2*i], thetaAll[(k+1)*12 + 2*i + 1]);
                }
                __hip_atomic_store((unsigned*)(sp + 63), (unsigned)(k+1),
                                   __ATOMIC_RELEASE, __HIP_MEMORY_SCOPE_AGENT);
            }
        }else{
            if(wave == 0){
                float* sp = slots + bid*64;
                unsigned* fp = (unsigned*)(sp + 63);
                int guard = 0;
                for(;;){
                    unsigned f = AG_LDU(fp);
                    if(f >= (unsigned)(k+1)) break;
                    __builtin_amdgcn_s_sleep(1);
                    if(++guard > (1<<17)) break;   // watchdog
                }
                // payload read AFTER flag observed (release-ordered at MALL)
                if(lane < 36) sAll[k*36 + lane] = AG_LDF(sp + lane);
                else if(lane < 48 && k < NIT){
                    float t = AG_LDF(sp + lane);
                    ths[lane-36] = t;
                    thetaAll[(k+1)*12 + (lane-36)] = t;
                }
            }
            __syncthreads();
        }
    }

    // backfold: serial 12-dim adjoint recursion, redundant per block from LDS
    if(tid == 0){
        float lv[12];
        compute_grad(sAll + NIT*36, thetaAll + NIT*12, ks, ksb, c, lv);
        for(int k=NIT-1;k>=0;k--){
            const float* s = sAll + k*36;
            const float* T = thetaAll + k*12;
            float* P = (float*)&pkS[k*5];
            P[0]=T[0]; P[1]=T[1]; P[2]=T[2]; P[3]=T[3];
            P[4]=T[6]; P[5]=T[7]; P[6]=T[8]; P[7]=T[9];
            P[8]=T[10]; P[9]=T[11];
            P[10]=lv[0]; P[11]=lv[1]; P[12]=lv[2]; P[13]=lv[3];
            P[14]=lv[6]; P[15]=lv[7]; P[16]=lv[8]; P[17]=lv[9];
            P[18]=lv[10]; P[19]=lv[11];
            float H[12];
            for(int a=0;a<2;a++)for(int b=0;b<2;b++){
                int j=a*2+b;
                float data = s[12+a*4+b*2+0]*lv[6+b*2+0]
                           + s[12+a*4+b*2+1]*lv[6+b*2+1]
                           + s[20+a*2+b]*lv[10+b];
                float kv=0.f;
                for(int m=0;m<4;m++) kv += ks[j*4+m]*lv[m];
                H[j]=kv - c*data;
            }
            H[4] = ksb[0]*lv[4] + ksb[1]*lv[5];
            H[5] = ksb[2]*lv[4] + ksb[3]*lv[5];
            for(int cc=0;cc<2;cc++)for(int d=0;d<2;d++){
                int j=cc*2+d;
                float term1 = lv[0+cc]*s[12+0*4+cc*2+d] + lv[2+cc]*s[12+1*4+cc*2+d];
                float term2 = lv[6+cc*2+0]*s[24+cc*3+(0+d)] + lv[6+cc*2+1]*s[24+cc*3+(1+d)];
                float term3 = lv[10+cc]*s[30+cc*2+d];
                float kv=0.f;
                for(int m=0;m<4;m++) kv += ks[j*4+m]*lv[6+m];
                H[6+j]=kv - c*(term1+term2+term3);
            }
            for(int cc=0;cc<2;cc++){
                float z1 = lv[0+cc]*s[20+0*2+cc] + lv[2+cc]*s[20+1*2+cc];
                float z2 = lv[6+cc*2+0]*s[30+cc*2+0] + lv[6+cc*2+1]*s[30+cc*2+1];
                float z3 = lv[10+cc]*s[34+cc];
                float kv = ksb[cc*2+0]*lv[10] + ksb[cc*2+1]*lv[11];
                H[10+cc]=kv - c*(z1+z2+z3);
            }
            for(int j=0;j<12;j++) lv[j] -= LR*H[j];
        }
    }
    __syncthreads();

    // final phase: theta row 20 + pk from LDS, q/p still in registers
    const float* T20 = thetaAll + NIT*12;
    const float f1_00=T20[0], f1_01=T20[1], f1_10=T20[2], f1_11=T20[3];
    const float fb1_0=T20[4], fb1_1=T20[5];
    const float f2_00=T20[6], f2_01=T20[7], f2_10=T20[8], f2_11=T20[9];
    const float fb2_0=T20[10], fb2_1=T20[11];

    if(fast){
        v2f Q0r[4],Q1r[4],P0r[4],P1r[4],B0r[4],B1r[4];
        #pragma unroll
        for(int sl=0; sl<4; sl++){
            Q0r[sl]=(v2f){qd[sl].x,qd[sl].z}; Q1r[sl]=(v2f){qd[sl].y,qd[sl].w};
            P0r[sl]=(v2f){pd[sl].x,pd[sl].z}; P1r[sl]=(v2f){pd[sl].y,pd[sl].w};
            B0r[sl]=(v2f){0.f,0.f}; B1r[sl]=(v2f){0.f,0.f};
        }
        for(int k=0;k<NIT;k++){
            float4 P0=pkS[k*5+0], P1=pkS[k*5+1], P2=pkS[k*5+2], P3=pkS[k*5+3], P4v=pkS[k*5+4];
            float t1_00=P0.x,t1_01=P0.y,t1_10=P0.z,t1_11=P0.w;
            float t2_00=P1.x,t2_01=P1.y,t2_10=P1.z,t2_11=P1.w;
            float b2_0=P2.x,b2_1=P2.y;
            float L1_00=P2.z,L1_01=P2.w,L1_10=P3.x,L1_11=P3.y;
            float L2_00=P3.z,L2_01=P3.w,L2_10=P4v.x,L2_11=P4v.y,lb2_0=P4v.z,lb2_1=P4v.w;
            #pragma unroll
            for(int sl=0; sl<4; sl++)
                bk_step2(Q0r[sl],Q1r[sl],P0r[sl],P1r[sl],
                    t1_00,t1_01,t1_10,t1_11,t2_00,t2_01,t2_10,t2_11,b2_0,b2_1,
                    L1_00,L1_01,L1_10,L1_11,L2_00,L2_01,L2_10,L2_11,lb2_0,lb2_1,
                    B0r[sl],B1r[sl]);
        }
        #pragma unroll
        for(int sl=0; sl<4; sl++){
            int j = gtid + sl*NT;
            v2f Q0=Q0r[sl], Q1=Q1r[sl], P0=P0r[sl], P1=P1r[sl];
            v2f Bs0=B0r[sl], Bs1=B1r[sl];
            v2f u0 = f2_00*Q0 + f2_01*Q1 + fb2_0;
            v2f u1 = f2_10*Q0 + f2_11*Q1 + fb2_1;
            v2f h0 = tanh2(u0), h1 = tanh2(u1);
            v2f s0 = 1.0f - h0*h0, s1 = 1.0f - h1*h1;
            v2f a0 = f1_00*P0 + f1_10*P1;
            v2f a1 = f1_01*P0 + f1_11*P1;
            v2f w0 = a0*s0, w1 = a1*s1;
            v2f dq0 = f1_00*h0 + f1_01*h1 + fb1_0;
            v2f dq1 = f1_10*h0 + f1_11*h1 + fb1_1;
            v2f dp0 = c*(LR*Bs0 - (f2_00*w0 + f2_10*w1));
            v2f dp1 = c*(LR*Bs1 - (f2_01*w0 + f2_11*w1));
            oq[j] = make_float4(dq0.x, dq1.x, dq0.y, dq1.y);
            op[j] = make_float4(dp0.x, dp1.x, dp0.y, dp1.y);
            float4 xx = x4[j];
            v2f X0={xx.x,xx.z}, X1={xx.y,xx.w};
            v2f xu0 = f2_00*X0 + f2_01*X1 + fb2_0;
            v2f xu1 = f2_10*X0 + f2_11*X1 + fb2_1;
            v2f xh0 = tanh2(xu0), xh1 = tanh2(xu1);
            v2f xd0 = f1_00*xh0 + f1_01*xh1 + fb1_0;
            v2f xd1 = f1_10*xh0 + f1_11*xh1 + fb1_1;
            ox[j] = make_float4(xd0.x, xd1.x, xd0.y, xd1.y);
        }
    }else{
        for(int j = gtid; j < nv4; j += NT){
            float4 qq=q4[j], pp=p4[j];
            v2f Q0={qq.x,qq.z}, Q1={qq.y,qq.w};
            v2f P0={pp.x,pp.z}, P1={pp.y,pp.w};
            v2f Bs0={0.f,0.f}, Bs1={0.f,0.f};
            for(int k=0;k<NIT;k++){
                float4 P0v=pkS[k*5+0], P1v=pkS[k*5+1], P2v=pkS[k*5+2], P3v=pkS[k*5+3], P4v=pkS[k*5+4];
                bk_step2(Q0,Q1,P0,P1,
                    P0v.x,P0v.y,P0v.z,P0v.w, P1v.x,P1v.y,P1v.z,P1v.w, P2v.x,P2v.y,
                    P2v.z,P2v.w,P3v.x,P3v.y, P3v.z,P3v.w,P4v.x,P4v.y,P4v.z,P4v.w,
                    Bs0,Bs1);
            }
            v2f u0 = f2_00*Q0 + f2_01*Q1 + fb2_0;
            v2f u1 = f2_10*Q0 + f2_11*Q1 + fb2_1;
            v2f h0 = tanh2(u0), h1 = tanh2(u1);
            v2f s0 = 1.0f - h0*h0, s1 = 1.0f - h1*h1;
            v2f a0 = f1_00*P0 + f1_10*P1;
            v2f a1 = f1_01*P0 + f1_11*P1;
            v2f w0 = a0*s0, w1 = a1*s1;
            v2f dq0 = f1_00*h0 + f1_01*h1 + fb1_0;
            v2f dq1 = f1_10*h0 + f1_11*h1 + fb1_1;
            v2f dp0 = c*(LR*Bs0 - (f2_00*w0 + f2_10*w1));
            v2f dp1 = c*(LR*Bs1 - (f2_01*w0 + f2_11*w1));
            oq[j] = make_float4(dq0.x, dq1.x, dq0.y, dq1.y);
            op[j] = make_float4(dp0.x, dp1.x, dp0.y, dp1.y);
            float4 xx = x4[j];
            v2f X0={xx.x,xx.z}, X1={xx.y,xx.w};
            v2f xu0 = f2_00*X0 + f2_01*X1 + fb2_0;
            v2f xu1 = f2_10*X0 + f2_11*X1 + fb2_1;
            v2f xh0 = tanh2(xu0), xh1 = tanh2(xu1);
            v2f xd0 = f1_00*xh0 + f1_01*xh1 + fb1_0;
            v2f xd1 = f1_10*xh0 + f1_11*xh1 + fb1_1;
            ox[j] = make_float4(xd0.x, xd1.x, xd0.y, xd1.y);
        }
    }
}

extern "C" void kernel_launch(void* const* d_in, const int* in_sizes, int n_in,
                              void* d_out, int out_size, void* d_ws, size_t ws_size,
                              hipStream_t stream) {
    const float* inp = (const float*)d_in[1];
    const int K = in_sizes[1]/6;
    int nv4 = K >> 1;

    const float4* q4 = (const float4*)inp;
    const float4* p4 = (const float4*)(inp + 2*(size_t)K);
    const float4* x4 = (const float4*)(inp + 4*(size_t)K);

    float* gsum = (float*)d_ws;                    // [21][64]
    unsigned* cnt = (unsigned*)(gsum + (NIT+1)*64);// [32]
    float* slots = (float*)(cnt + 32);             // [NB][64]
    float c = 1.0f/(2.0f*(float)K);

    const float* t1i = (const float*)d_in[2];
    const float* b1i = (const float*)d_in[3];
    const float* t2i = (const float*)d_in[4];
    const float* b2i = (const float*)d_in[5];
    const float* invK = (const float*)d_in[6];
    const float* invKb= (const float*)d_in[7];

    float* out = (float*)d_out;
    float4* oq = (float4*)out;
    float4* op = (float4*)(out + 2*(size_t)K);
    float4* ox = (float4*)(out + 4*(size_t)K);

    // zero gsum + cnt + slots (contiguous)
    size_t zb = (size_t)(NIT+1)*64*sizeof(float) + 32*sizeof(unsigned)
              + (size_t)NB*64*sizeof(float);
    hipMemsetAsync(d_ws, 0, zb, stream);
    k_all<<<dim3(NB), dim3(TPB), 0, stream>>>(q4, p4, x4, nv4,
                                              t1i, b1i, t2i, b2i, invK, invKb,
                                              gsum, cnt, slots, oq, op, ox, c);
}

// Round 6
// 417.119 us; speedup vs baseline: 1.3320x; 1.3320x over previous
//
#include <hip/hip_runtime.h>

// ShootingBlockMNModel1 — single fused kernel, regular launch (graph-safe).
// Latency-optimized grid sync (every cross-block hop = agent-scope, fence-free):
//   workers: 36 partials + flag into a private 256B slot (1 drain).
//   block 0: polls 256 flags (1 RT/round), gathers ALL rows with upfront
//            independent loads (1 RT), grad, writes 13-dword theta slots
//            (payload+flag merged; 1 drain).
//   readers: lanes 0-12 poll their OWN slot; payload rides in the polling
//            load itself (0 extra RT). No sums, no backfold on readers.
//   backfold: block 0 only; pk broadcast once (400 floats, 2 RT).
// Busy-spin polls (no s_sleep) to hold clocks up. q/p pinned in VGPRs.
//
// ws: pslot[NB][64] f32 ; tslot[NB][16] f32 ; pkbc[512] f32 (memset 84KB)

#define LR 0.25f
#define NIT 20
#define TPB 512
#define NB  256
#define GUARD (1<<18)

typedef float v2f __attribute__((ext_vector_type(2)));

#define AG_LDF(p)       __hip_atomic_load((p),  __ATOMIC_RELAXED, __HIP_MEMORY_SCOPE_AGENT)
#define AG_LDU(p)       __hip_atomic_load((p),  __ATOMIC_RELAXED, __HIP_MEMORY_SCOPE_AGENT)
#define AG_STF(p,v)     __hip_atomic_store((p), (v), __ATOMIC_RELAXED, __HIP_MEMORY_SCOPE_AGENT)
#define AG_STU_REL(p,v) __hip_atomic_store((p), (v), __ATOMIC_RELEASE, __HIP_MEMORY_SCOPE_AGENT)

__device__ __forceinline__ void st64_ag(float* p, float a, float b){
    union{ float f[2]; unsigned long long u; } x;
    x.f[0]=a; x.f[1]=b;
    __hip_atomic_store((unsigned long long*)p, x.u,
                       __ATOMIC_RELAXED, __HIP_MEMORY_SCOPE_AGENT);
}

__device__ __forceinline__ v2f tanh2(v2f x){
    v2f e;
    e.x = __expf(x.x + x.x);
    e.y = __expf(x.y + x.y);
    v2f d = e + 1.0f;
    v2f r;
    r.x = __builtin_amdgcn_rcpf(d.x);
    r.y = __builtin_amdgcn_rcpf(d.y);
    return 1.0f - (r + r);
}

// wave64 sum via DPP on the VALU pipe; result valid in lane 63
#define DPP_ADD(x, ctrl) ((x) + __int_as_float(__builtin_amdgcn_update_dpp(0, __float_as_int(x), (ctrl), 0xF, 0xF, true)))
__device__ __forceinline__ float wave_sum64(float x){
    x = DPP_ADD(x, 0x111);   // row_shr:1
    x = DPP_ADD(x, 0x112);   // row_shr:2
    x = DPP_ADD(x, 0x114);   // row_shr:4
    x = DPP_ADD(x, 0x118);   // row_shr:8  -> lane 15+16r = row sum
    x = DPP_ADD(x, 0x142);   // row_bcast:15
    x = DPP_ADD(x, 0x143);   // row_bcast:31 -> lane 63 = total
    return x;
}

__device__ __forceinline__ void compute_grad(const float* s, const float* th,
                                             const float* ksym, const float* ksymb,
                                             float c, float* g){
    const float Ivec[4]={1.f,0.f,0.f,1.f};
    #pragma unroll
    for(int j=0;j<4;j++){
        float kv=0.f;
        #pragma unroll
        for(int m=0;m<4;m++) kv += ksym[j*4+m]*th[m];
        g[j] = kv - c*s[j];
    }
    #pragma unroll
    for(int i2=0;i2<2;i2++)
        g[4+i2] = ksymb[i2*2+0]*th[4] + ksymb[i2*2+1]*th[5] - c*s[4+i2];
    #pragma unroll
    for(int j=0;j<4;j++){
        float kv=0.f;
        #pragma unroll
        for(int m=0;m<4;m++) kv += ksym[j*4+m]*(th[6+m]-Ivec[m]);
        g[6+j] = kv - c*s[6+j];
    }
    #pragma unroll
    for(int i2=0;i2<2;i2++)
        g[10+i2] = ksymb[i2*2+0]*th[10] + ksymb[i2*2+1]*th[11] - c*s[10+i2];
}

// packed accumulate: float4 = 2 samples in v2f lanes
__device__ __forceinline__ void accum_sample2(v2f Q0, v2f Q1, v2f P0, v2f P1,
    float t1_00,float t1_01,float t1_10,float t1_11,
    float t2_00,float t2_01,float t2_10,float t2_11,float b2_0,float b2_1,
    v2f (&acc)[36]){
    v2f u0 = t2_00*Q0 + t2_01*Q1 + b2_0;
    v2f u1 = t2_10*Q0 + t2_11*Q1 + b2_1;
    v2f h0 = tanh2(u0), h1 = tanh2(u1);
    v2f s0 = 1.0f - h0*h0, s1 = 1.0f - h1*h1;
    v2f a0 = t1_00*P0 + t1_10*P1;
    v2f a1 = t1_01*P0 + t1_11*P1;
    v2f w0 = a0*s0, w1 = a1*s1;
    v2f r0 = -2.0f*(a0*h0)*s0, r1 = -2.0f*(a1*h1)*s1;
    acc[0]+=P0*h0; acc[1]+=P0*h1; acc[2]+=P1*h0; acc[3]+=P1*h1;
    acc[4]+=P0;    acc[5]+=P1;
    acc[6]+=w0*Q0; acc[7]+=w0*Q1; acc[8]+=w1*Q0; acc[9]+=w1*Q1;
    acc[10]+=w0;   acc[11]+=w1;
    v2f ps00=P0*s0, ps01=P0*s1, ps10=P1*s0, ps11=P1*s1;
    acc[12]+=ps00*Q0; acc[13]+=ps00*Q1; acc[14]+=ps01*Q0; acc[15]+=ps01*Q1;
    acc[16]+=ps10*Q0; acc[17]+=ps10*Q1; acc[18]+=ps11*Q0; acc[19]+=ps11*Q1;
    acc[20]+=ps00; acc[21]+=ps01; acc[22]+=ps10; acc[23]+=ps11;
    v2f r0q0=r0*Q0, r1q0=r1*Q0;
    acc[24]+=r0q0*Q0; acc[25]+=r0q0*Q1; acc[26]+=r0*(Q1*Q1);
    acc[27]+=r1q0*Q0; acc[28]+=r1q0*Q1; acc[29]+=r1*(Q1*Q1);
    acc[30]+=r0q0; acc[31]+=r0*Q1; acc[32]+=r1q0; acc[33]+=r1*Q1;
    acc[34]+=r0; acc[35]+=r1;
}

__device__ __forceinline__ void bk_step2(v2f Q0, v2f Q1, v2f P0, v2f P1,
    float t1_00,float t1_01,float t1_10,float t1_11,
    float t2_00,float t2_01,float t2_10,float t2_11,float b2_0,float b2_1,
    float L1_00,float L1_01,float L1_10,float L1_11,
    float L2_00,float L2_01,float L2_10,float L2_11,float lb2_0,float lb2_1,
    v2f &B0, v2f &B1){
    v2f u0 = t2_00*Q0 + t2_01*Q1 + b2_0;
    v2f u1 = t2_10*Q0 + t2_11*Q1 + b2_1;
    v2f h0 = tanh2(u0), h1 = tanh2(u1);
    v2f s0 = 1.0f - h0*h0, s1 = 1.0f - h1*h1;
    v2f a0 = t1_00*P0 + t1_10*P1;
    v2f a1 = t1_01*P0 + t1_11*P1;
    v2f w0 = a0*s0, w1 = a1*s1;
    v2f r0 = -2.0f*(a0*h0)*s0, r1 = -2.0f*(a1*h1)*s1;
    v2f lp0 = L1_00*P0 + L1_10*P1;
    v2f lp1 = L1_01*P0 + L1_11*P1;
    v2f z0 = L2_00*Q0 + L2_01*Q1 + lb2_0;
    v2f z1 = L2_10*Q0 + L2_11*Q1 + lb2_1;
    v2f m0 = lp0*s0 + r0*z0;
    v2f m1 = lp1*s1 + r1*z1;
    B0 += t2_00*m0 + t2_10*m1 + L2_00*w0 + L2_10*w1;
    B1 += t2_01*m0 + t2_11*m1 + L2_01*w0 + L2_11*w1;
}

__global__ __launch_bounds__(TPB, 2) void k_all(
    const float4* __restrict__ q4, const float4* __restrict__ p4,
    const float4* __restrict__ x4, int nv4,
    const float* __restrict__ t1i, const float* __restrict__ b1i,
    const float* __restrict__ t2i, const float* __restrict__ b2i,
    const float* __restrict__ invK, const float* __restrict__ invKb,
    float* __restrict__ pslot,           // [NB][64]: sums 0..35, flag@36
    float* __restrict__ tslot,           // [NB][16]: theta 0..11, flag@12
    float* __restrict__ pkbc,            // [512]: final pk broadcast
    float4* __restrict__ oq, float4* __restrict__ op, float4* __restrict__ ox,
    float c)
{
    const int tid  = threadIdx.x;
    const int bid  = blockIdx.x;
    const int NT   = gridDim.x * TPB;
    const int gtid = bid*TPB + tid;
    const int wave = tid >> 6, lane = tid & 63;

    __shared__ float ths[12];                  // current theta (ends as theta20)
    __shared__ float thetaAll[(NIT+1)*12];     // block0 only
    __shared__ float sAll[(NIT+1)*36];         // block0 only
    __shared__ float red[TPB/64][36];
    __shared__ float ks[16], ksb[4];
    __shared__ float4 pkS[NIT*5];              // packed theta_k + lam_{k+1}
    float* pkSf = (float*)pkS;

    if(tid < 16) ks[tid]  = 0.5f*(invK[tid]  + invK[(tid&3)*4 + (tid>>2)]);
    if(tid < 4)  ksb[tid] = 0.5f*(invKb[tid] + invKb[(tid&1)*2 + (tid>>1)]);
    if(tid < 12){
        float v = (tid<4)? t1i[tid] : (tid<6)? b1i[tid-4]
                : (tid<10)? t2i[tid-6] : b2i[tid-10];
        ths[tid] = v;
        thetaAll[tid] = v;
    }
    __syncthreads();

    // Pin this thread's samples in registers for the whole kernel.
    const bool fast = (nv4 == 4*NT);
    float4 qd[4], pd[4];
    if(fast){
        #pragma unroll
        for(int sl=0; sl<4; sl++){ qd[sl]=q4[gtid + sl*NT]; pd[sl]=p4[gtid + sl*NT]; }
    }

    for(int k=0; k<=NIT; k++){
        const float t1_00=ths[0], t1_01=ths[1], t1_10=ths[2], t1_11=ths[3];
        const float t2_00=ths[6], t2_01=ths[7], t2_10=ths[8], t2_11=ths[9];
        const float b2_0=ths[10], b2_1=ths[11];

        v2f acc[36];
        #pragma unroll
        for(int j=0;j<36;j++) acc[j] = (v2f){0.f, 0.f};

        if(fast){
            #pragma unroll
            for(int sl=0; sl<4; sl++){
                v2f Q0={qd[sl].x,qd[sl].z}, Q1={qd[sl].y,qd[sl].w};
                v2f P0={pd[sl].x,pd[sl].z}, P1={pd[sl].y,pd[sl].w};
                accum_sample2(Q0,Q1,P0,P1,
                    t1_00,t1_01,t1_10,t1_11,t2_00,t2_01,t2_10,t2_11,b2_0,b2_1,acc);
            }
        }else{
            for(int j = gtid; j < nv4; j += NT){
                float4 qq = q4[j], pp = p4[j];
                v2f Q0={qq.x,qq.z}, Q1={qq.y,qq.w};
                v2f P0={pp.x,pp.z}, P1={pp.y,pp.w};
                accum_sample2(Q0,Q1,P0,P1,
                    t1_00,t1_01,t1_10,t1_11,t2_00,t2_01,t2_10,t2_11,b2_0,b2_1,acc);
            }
        }

        // wave reduction (VALU pipe) -> block partials -> private slot + flag
        float wres[36];
        #pragma unroll
        for(int j=0;j<36;j++) wres[j] = wave_sum64(acc[j].x + acc[j].y);
        if(lane == 63){
            #pragma unroll
            for(int j=0;j<36;j++) red[wave][j] = wres[j];
        }
        __syncthreads();
        if(tid < 36){
            float sum = 0.f;
            #pragma unroll
            for(int w=0; w<TPB/64; w++) sum += red[w][tid];
            AG_STF(pslot + bid*64 + tid, sum);
        }
        if(tid == 0)   // wave0 release: drains lanes 0..35's stores (same wave)
            AG_STU_REL((unsigned*)(pslot + bid*64 + 36), (unsigned)(k+1));

        if(bid == 0){
            // 1) poll all 256 arrival flags (4/lane, one RT per round, busy)
            if(wave == 0){
                const unsigned tgt = (unsigned)(k+1);
                unsigned* f0 = (unsigned*)(pslot + (lane*4+0)*64 + 36);
                unsigned* f1 = (unsigned*)(pslot + (lane*4+1)*64 + 36);
                unsigned* f2 = (unsigned*)(pslot + (lane*4+2)*64 + 36);
                unsigned* f3 = (unsigned*)(pslot + (lane*4+3)*64 + 36);
                int guard = 0;
                for(;;){
                    unsigned a=AG_LDU(f0), b=AG_LDU(f1), e=AG_LDU(f2), d=AG_LDU(f3);
                    if(__all(a>=tgt && b>=tgt && e>=tgt && d>=tgt)) break;
                    if(++guard > GUARD) break;   // watchdog: never hang
                }
            }
            __syncthreads();
            // 2) gather: 20 independent loads issued upfront (ONE round trip),
            //    rows {wave, wave+8, wave+16, wave+24, wave+32(<36)}
            {
                const int r4i = (wave<4)? (wave+32) : (wave+24); // dummy if wave>=4
                const float* B0p = pslot + (lane     )*64;
                const float* B1p = pslot + (lane+  64)*64;
                const float* B2p = pslot + (lane+ 128)*64;
                const float* B3p = pslot + (lane+ 192)*64;
                float a0=AG_LDF(B0p+wave),    a1=AG_LDF(B1p+wave),    a2=AG_LDF(B2p+wave),    a3=AG_LDF(B3p+wave);
                float b0=AG_LDF(B0p+wave+8),  b1=AG_LDF(B1p+wave+8),  b2=AG_LDF(B2p+wave+8),  b3=AG_LDF(B3p+wave+8);
                float c0=AG_LDF(B0p+wave+16), c1=AG_LDF(B1p+wave+16), c2=AG_LDF(B2p+wave+16), c3=AG_LDF(B3p+wave+16);
                float d0=AG_LDF(B0p+wave+24), d1=AG_LDF(B1p+wave+24), d2=AG_LDF(B2p+wave+24), d3=AG_LDF(B3p+wave+24);
                float e0=AG_LDF(B0p+r4i),     e1=AG_LDF(B1p+r4i),     e2=AG_LDF(B2p+r4i),     e3=AG_LDF(B3p+r4i);
                float s0 = wave_sum64(a0+a1+a2+a3);
                float s1 = wave_sum64(b0+b1+b2+b3);
                float s2 = wave_sum64(c0+c1+c2+c3);
                float s3 = wave_sum64(d0+d1+d2+d3);
                float s4 = wave_sum64(e0+e1+e2+e3);
                if(lane == 63){
                    sAll[k*36 + wave]      = s0;
                    sAll[k*36 + wave + 8]  = s1;
                    sAll[k*36 + wave + 16] = s2;
                    sAll[k*36 + wave + 24] = s3;
                    if(wave < 4) sAll[k*36 + wave + 32] = s4;
                }
            }
            __syncthreads();
            // 3) theta update
            if(tid == 0 && k < NIT){
                float g[12];
                compute_grad(sAll + k*36, thetaAll + k*12, ks, ksb, c, g);
                #pragma unroll
                for(int j=0;j<12;j++){
                    float t = thetaAll[k*12+j] - LR*g[j];
                    ths[j] = t;
                    thetaAll[(k+1)*12+j] = t;
                }
            }
            __syncthreads();
            // 4) write private 13-dword theta slots (payload + release flag)
            if(k < NIT && tid < NB){
                float* sp = tslot + tid*16;
                st64_ag(sp+0,  ths[0], ths[1]);
                st64_ag(sp+2,  ths[2], ths[3]);
                st64_ag(sp+4,  ths[4], ths[5]);
                st64_ag(sp+6,  ths[6], ths[7]);
                st64_ag(sp+8,  ths[8], ths[9]);
                st64_ag(sp+10, ths[10], ths[11]);
                AG_STU_REL((unsigned*)(sp+12), (unsigned)(k+1));
            }
        }else if(k < NIT){
            // merged poll+payload: lanes 0..12 each own one dword of the slot
            if(wave == 0){
                const unsigned tgt = (unsigned)(k+1);
                unsigned* sp = (unsigned*)(tslot + bid*16);
                const int idx = (lane < 13)? lane : 12;
                unsigned v; int guard = 0;
                for(;;){
                    v = AG_LDU(sp + idx);
                    unsigned f = (unsigned)__builtin_amdgcn_readlane((int)v, 12);
                    if(f >= tgt) break;
                    if(++guard > GUARD) break;   // watchdog
                }
                if(lane < 12) ths[lane] = __uint_as_float(v);
            }
            __syncthreads();
        }
    }

    // ---- backfold (block 0 only), then one pk broadcast ----
    if(bid == 0){
        if(tid == 0){
            float lv[12];
            compute_grad(sAll + NIT*36, thetaAll + NIT*12, ks, ksb, c, lv);
            for(int k=NIT-1;k>=0;k--){
                const float* s = sAll + k*36;
                const float* T = thetaAll + k*12;
                float* P = (float*)&pkS[k*5];
                P[0]=T[0]; P[1]=T[1]; P[2]=T[2]; P[3]=T[3];
                P[4]=T[6]; P[5]=T[7]; P[6]=T[8]; P[7]=T[9];
                P[8]=T[10]; P[9]=T[11];
                P[10]=lv[0]; P[11]=lv[1]; P[12]=lv[2]; P[13]=lv[3];
                P[14]=lv[6]; P[15]=lv[7]; P[16]=lv[8]; P[17]=lv[9];
                P[18]=lv[10]; P[19]=lv[11];
                float H[12];
                for(int a=0;a<2;a++)for(int b=0;b<2;b++){
                    int j=a*2+b;
                    float data = s[12+a*4+b*2+0]*lv[6+b*2+0]
                               + s[12+a*4+b*2+1]*lv[6+b*2+1]
                               + s[20+a*2+b]*lv[10+b];
                    float kv=0.f;
                    for(int m=0;m<4;m++) kv += ks[j*4+m]*lv[m];
                    H[j]=kv - c*data;
                }
                H[4] = ksb[0]*lv[4] + ksb[1]*lv[5];
                H[5] = ksb[2]*lv[4] + ksb[3]*lv[5];
                for(int cc=0;cc<2;cc++)for(int d=0;d<2;d++){
                    int j=cc*2+d;
                    float term1 = lv[0+cc]*s[12+0*4+cc*2+d] + lv[2+cc]*s[12+1*4+cc*2+d];
                    float term2 = lv[6+cc*2+0]*s[24+cc*3+(0+d)] + lv[6+cc*2+1]*s[24+cc*3+(1+d)];
                    float term3 = lv[10+cc]*s[30+cc*2+d];
                    float kv=0.f;
                    for(int m=0;m<4;m++) kv += ks[j*4+m]*lv[6+m];
                    H[6+j]=kv - c*(term1+term2+term3);
                }
                for(int cc=0;cc<2;cc++){
                    float z1 = lv[0+cc]*s[20+0*2+cc] + lv[2+cc]*s[20+1*2+cc];
                    float z2 = lv[6+cc*2+0]*s[30+cc*2+0] + lv[6+cc*2+1]*s[30+cc*2+1];
                    float z3 = lv[10+cc]*s[34+cc];
                    float kv = ksb[cc*2+0]*lv[10] + ksb[cc*2+1]*lv[11];
                    H[10+cc]=kv - c*(z1+z2+z3);
                }
                for(int j=0;j<12;j++) lv[j] -= LR*H[j];
            }
        }
        __syncthreads();
        if(tid < NIT*20) AG_STF(pkbc + tid, pkSf[tid]);
        asm volatile("s_waitcnt vmcnt(0)" ::: "memory");  // each wave drains its stores
        __syncthreads();
        if(tid < NB)
            AG_STU_REL((unsigned*)(tslot + tid*16 + 12), (unsigned)(NIT+1));
    }else{
        if(wave == 0){
            unsigned* fp = (unsigned*)(tslot + bid*16 + 12);
            int guard = 0;
            for(;;){
                unsigned f = AG_LDU(fp);
                if(f >= (unsigned)(NIT+1)) break;
                if(++guard > GUARD) break;   // watchdog
            }
        }
        __syncthreads();
        if(tid < NIT*20) pkSf[tid] = AG_LDF(pkbc + tid);
        __syncthreads();
    }

    // final phase: ths == theta row 20; pkS in LDS; q/p still in registers
    const float f1_00=ths[0], f1_01=ths[1], f1_10=ths[2], f1_11=ths[3];
    const float fb1_0=ths[4], fb1_1=ths[5];
    const float f2_00=ths[6], f2_01=ths[7], f2_10=ths[8], f2_11=ths[9];
    const float fb2_0=ths[10], fb2_1=ths[11];

    if(fast){
        v2f Q0r[4],Q1r[4],P0r[4],P1r[4],B0r[4],B1r[4];
        #pragma unroll
        for(int sl=0; sl<4; sl++){
            Q0r[sl]=(v2f){qd[sl].x,qd[sl].z}; Q1r[sl]=(v2f){qd[sl].y,qd[sl].w};
            P0r[sl]=(v2f){pd[sl].x,pd[sl].z}; P1r[sl]=(v2f){pd[sl].y,pd[sl].w};
            B0r[sl]=(v2f){0.f,0.f}; B1r[sl]=(v2f){0.f,0.f};
        }
        for(int k=0;k<NIT;k++){
            float4 P0=pkS[k*5+0], P1=pkS[k*5+1], P2=pkS[k*5+2], P3=pkS[k*5+3], P4v=pkS[k*5+4];
            float t1_00=P0.x,t1_01=P0.y,t1_10=P0.z,t1_11=P0.w;
            float t2_00=P1.x,t2_01=P1.y,t2_10=P1.z,t2_11=P1.w;
            float b2_0=P2.x,b2_1=P2.y;
            float L1_00=P2.z,L1_01=P2.w,L1_10=P3.x,L1_11=P3.y;
            float L2_00=P3.z,L2_01=P3.w,L2_10=P4v.x,L2_11=P4v.y,lb2_0=P4v.z,lb2_1=P4v.w;
            #pragma unroll
            for(int sl=0; sl<4; sl++)
                bk_step2(Q0r[sl],Q1r[sl],P0r[sl],P1r[sl],
                    t1_00,t1_01,t1_10,t1_11,t2_00,t2_01,t2_10,t2_11,b2_0,b2_1,
                    L1_00,L1_01,L1_10,L1_11,L2_00,L2_01,L2_10,L2_11,lb2_0,lb2_1,
                    B0r[sl],B1r[sl]);
        }
        #pragma unroll
        for(int sl=0; sl<4; sl++){
            int j = gtid + sl*NT;
            v2f Q0=Q0r[sl], Q1=Q1r[sl], P0=P0r[sl], P1=P1r[sl];
            v2f Bs0=B0r[sl], Bs1=B1r[sl];
            v2f u0 = f2_00*Q0 + f2_01*Q1 + fb2_0;
            v2f u1 = f2_10*Q0 + f2_11*Q1 + fb2_1;
            v2f h0 = tanh2(u0), h1 = tanh2(u1);
            v2f s0 = 1.0f - h0*h0, s1 = 1.0f - h1*h1;
            v2f a0 = f1_00*P0 + f1_10*P1;
            v2f a1 = f1_01*P0 + f1_11*P1;
            v2f w0 = a0*s0, w1 = a1*s1;
            v2f dq0 = f1_00*h0 + f1_01*h1 + fb1_0;
            v2f dq1 = f1_10*h0 + f1_11*h1 + fb1_1;
            v2f dp0 = c*(LR*Bs0 - (f2_00*w0 + f2_10*w1));
            v2f dp1 = c*(LR*Bs1 - (f2_01*w0 + f2_11*w1));
            oq[j] = make_float4(dq0.x, dq1.x, dq0.y, dq1.y);
            op[j] = make_float4(dp0.x, dp1.x, dp0.y, dp1.y);
            float4 xx = x4[j];
            v2f X0={xx.x,xx.z}, X1={xx.y,xx.w};
            v2f xu0 = f2_00*X0 + f2_01*X1 + fb2_0;
            v2f xu1 = f2_10*X0 + f2_11*X1 + fb2_1;
            v2f xh0 = tanh2(xu0), xh1 = tanh2(xu1);
            v2f xd0 = f1_00*xh0 + f1_01*xh1 + fb1_0;
            v2f xd1 = f1_10*xh0 + f1_11*xh1 + fb1_1;
            ox[j] = make_float4(xd0.x, xd1.x, xd0.y, xd1.y);
        }
    }else{
        for(int j = gtid; j < nv4; j += NT){
            float4 qq=q4[j], pp=p4[j];
            v2f Q0={qq.x,qq.z}, Q1={qq.y,qq.w};
            v2f P0={pp.x,pp.z}, P1={pp.y,pp.w};
            v2f Bs0={0.f,0.f}, Bs1={0.f,0.f};
            for(int k=0;k<NIT;k++){
                float4 P0v=pkS[k*5+0], P1v=pkS[k*5+1], P2v=pkS[k*5+2], P3v=pkS[k*5+3], P4v=pkS[k*5+4];
                bk_step2(Q0,Q1,P0,P1,
                    P0v.x,P0v.y,P0v.z,P0v.w, P1v.x,P1v.y,P1v.z,P1v.w, P2v.x,P2v.y,
                    P2v.z,P2v.w,P3v.x,P3v.y, P3v.z,P3v.w,P4v.x,P4v.y,P4v.z,P4v.w,
                    Bs0,Bs1);
            }
            v2f u0 = f2_00*Q0 + f2_01*Q1 + fb2_0;
            v2f u1 = f2_10*Q0 + f2_11*Q1 + fb2_1;
            v2f h0 = tanh2(u0), h1 = tanh2(u1);
            v2f s0 = 1.0f - h0*h0, s1 = 1.0f - h1*h1;
            v2f a0 = f1_00*P0 + f1_10*P1;
            v2f a1 = f1_01*P0 + f1_11*P1;
            v2f w0 = a0*s0, w1 = a1*s1;
            v2f dq0 = f1_00*h0 + f1_01*h1 + fb1_0;
            v2f dq1 = f1_10*h0 + f1_11*h1 + fb1_1;
            v2f dp0 = c*(LR*Bs0 - (f2_00*w0 + f2_10*w1));
            v2f dp1 = c*(LR*Bs1 - (f2_01*w0 + f2_11*w1));
            oq[j] = make_float4(dq0.x, dq1.x, dq0.y, dq1.y);
            op[j] = make_float4(dp0.x, dp1.x, dp0.y, dp1.y);
            float4 xx = x4[j];
            v2f X0={xx.x,xx.z}, X1={xx.y,xx.w};
            v2f xu0 = f2_00*X0 + f2_01*X1 + fb2_0;
            v2f xu1 = f2_10*X0 + f2_11*X1 + fb2_1;
            v2f xh0 = tanh2(xu0), xh1 = tanh2(xu1);
            v2f xd0 = f1_00*xh0 + f1_01*xh1 + fb1_0;
            v2f xd1 = f1_10*xh0 + f1_11*xh1 + fb1_1;
            ox[j] = make_float4(xd0.x, xd1.x, xd0.y, xd1.y);
        }
    }
}

extern "C" void kernel_launch(void* const* d_in, const int* in_sizes, int n_in,
                              void* d_out, int out_size, void* d_ws, size_t ws_size,
                              hipStream_t stream) {
    const float* inp = (const float*)d_in[1];
    const int K = in_sizes[1]/6;
    int nv4 = K >> 1;

    const float4* q4 = (const float4*)inp;
    const float4* p4 = (const float4*)(inp + 2*(size_t)K);
    const float4* x4 = (const float4*)(inp + 4*(size_t)K);

    float* pslot = (float*)d_ws;           // [NB][64]
    float* tslot = pslot + NB*64;          // [NB][16]
    float* pkbc  = tslot + NB*16;          // [512]
    float c = 1.0f/(2.0f*(float)K);

    const float* t1i = (const float*)d_in[2];
    const float* b1i = (const float*)d_in[3];
    const float* t2i = (const float*)d_in[4];
    const float* b2i = (const float*)d_in[5];
    const float* invK = (const float*)d_in[6];
    const float* invKb= (const float*)d_in[7];

    float* out = (float*)d_out;
    float4* oq = (float4*)out;
    float4* op = (float4*)(out + 2*(size_t)K);
    float4* ox = (float4*)(out + 4*(size_t)K);

    // zero all flag-bearing regions (monotonic flags must start at 0)
    size_t zb = (size_t)(NB*64 + NB*16 + 512)*sizeof(float);
    hipMemsetAsync(d_ws, 0, zb, stream);
    k_all<<<dim3(NB), dim3(TPB), 0, stream>>>(q4, p4, x4, nv4,
                                              t1i, b1i, t2i, b2i, invK, invKb,
                                              pslot, tslot, pkbc, oq, op, ox, c);
}

// Round 7
// 261.646 us; speedup vs baseline: 2.1235x; 1.5942x over previous
//
#include <hip/hip_runtime.h>

// ShootingBlockMNModel1 — single fused kernel, regular launch (graph-safe).
// Epoch-tagged u64 cross-block protocol: every shared datum is one atomic
// {f32 value, u32 epoch} word — data is its own flag, so there are NO release
// fences, NO vmcnt drains, and NO separate flag/payload round trips.
//   workers: 36 tagged partials -> part64[36][NB] (relaxed agent stores).
//   block 0: polls the partial DATA directly (coalesced, 16-20 u64/lane);
//            when epochs match, gather is already in registers. Computes
//            theta, writes 12 tagged u64 per reader block.
//   readers: poll their OWN 96B slot; detect == payload (same load).
//   backfold: block 0 only; pk broadcast via 400 tagged u64.
// s_sleep backoff on all polls (r6 lesson: busy-spin saturates the MALL).
// q/p pinned in VGPRs across the whole kernel (loaded once).
//
// ws (u64): part64[36*NB] ; tslot64[NB*12] ; pk64[400]  (memset ~100KB)

#define LR 0.25f
#define NIT 20
#define TPB 512
#define NB  256
#define GUARD (1<<18)

typedef float v2f __attribute__((ext_vector_type(2)));
typedef unsigned long long u64;

__device__ __forceinline__ u64 ld64_ag(const u64* p){
    return __hip_atomic_load(p, __ATOMIC_RELAXED, __HIP_MEMORY_SCOPE_AGENT);
}
__device__ __forceinline__ void st64_ep(u64* p, float v, unsigned ep){
    u64 x = ((u64)ep << 32) | (u64)__float_as_uint(v);
    __hip_atomic_store(p, x, __ATOMIC_RELAXED, __HIP_MEMORY_SCOPE_AGENT);
}
__device__ __forceinline__ unsigned ep_of(u64 x){ return (unsigned)(x >> 32); }
__device__ __forceinline__ float    val_of(u64 x){ return __uint_as_float((unsigned)(x & 0xffffffffull)); }

__device__ __forceinline__ v2f tanh2(v2f x){
    v2f e;
    e.x = __expf(x.x + x.x);
    e.y = __expf(x.y + x.y);
    v2f d = e + 1.0f;
    v2f r;
    r.x = __builtin_amdgcn_rcpf(d.x);
    r.y = __builtin_amdgcn_rcpf(d.y);
    return 1.0f - (r + r);
}

// wave64 sum via DPP on the VALU pipe; result valid in lane 63
#define DPP_ADD(x, ctrl) ((x) + __int_as_float(__builtin_amdgcn_update_dpp(0, __float_as_int(x), (ctrl), 0xF, 0xF, true)))
__device__ __forceinline__ float wave_sum64(float x){
    x = DPP_ADD(x, 0x111);   // row_shr:1
    x = DPP_ADD(x, 0x112);   // row_shr:2
    x = DPP_ADD(x, 0x114);   // row_shr:4
    x = DPP_ADD(x, 0x118);   // row_shr:8  -> lane 15+16r = row sum
    x = DPP_ADD(x, 0x142);   // row_bcast:15
    x = DPP_ADD(x, 0x143);   // row_bcast:31 -> lane 63 = total
    return x;
}

__device__ __forceinline__ void compute_grad(const float* s, const float* th,
                                             const float* ksym, const float* ksymb,
                                             float c, float* g){
    const float Ivec[4]={1.f,0.f,0.f,1.f};
    #pragma unroll
    for(int j=0;j<4;j++){
        float kv=0.f;
        #pragma unroll
        for(int m=0;m<4;m++) kv += ksym[j*4+m]*th[m];
        g[j] = kv - c*s[j];
    }
    #pragma unroll
    for(int i2=0;i2<2;i2++)
        g[4+i2] = ksymb[i2*2+0]*th[4] + ksymb[i2*2+1]*th[5] - c*s[4+i2];
    #pragma unroll
    for(int j=0;j<4;j++){
        float kv=0.f;
        #pragma unroll
        for(int m=0;m<4;m++) kv += ksym[j*4+m]*(th[6+m]-Ivec[m]);
        g[6+j] = kv - c*s[6+j];
    }
    #pragma unroll
    for(int i2=0;i2<2;i2++)
        g[10+i2] = ksymb[i2*2+0]*th[10] + ksymb[i2*2+1]*th[11] - c*s[10+i2];
}

// packed accumulate: float4 = 2 samples in v2f lanes
__device__ __forceinline__ void accum_sample2(v2f Q0, v2f Q1, v2f P0, v2f P1,
    float t1_00,float t1_01,float t1_10,float t1_11,
    float t2_00,float t2_01,float t2_10,float t2_11,float b2_0,float b2_1,
    v2f (&acc)[36]){
    v2f u0 = t2_00*Q0 + t2_01*Q1 + b2_0;
    v2f u1 = t2_10*Q0 + t2_11*Q1 + b2_1;
    v2f h0 = tanh2(u0), h1 = tanh2(u1);
    v2f s0 = 1.0f - h0*h0, s1 = 1.0f - h1*h1;
    v2f a0 = t1_00*P0 + t1_10*P1;
    v2f a1 = t1_01*P0 + t1_11*P1;
    v2f w0 = a0*s0, w1 = a1*s1;
    v2f r0 = -2.0f*(a0*h0)*s0, r1 = -2.0f*(a1*h1)*s1;
    acc[0]+=P0*h0; acc[1]+=P0*h1; acc[2]+=P1*h0; acc[3]+=P1*h1;
    acc[4]+=P0;    acc[5]+=P1;
    acc[6]+=w0*Q0; acc[7]+=w0*Q1; acc[8]+=w1*Q0; acc[9]+=w1*Q1;
    acc[10]+=w0;   acc[11]+=w1;
    v2f ps00=P0*s0, ps01=P0*s1, ps10=P1*s0, ps11=P1*s1;
    acc[12]+=ps00*Q0; acc[13]+=ps00*Q1; acc[14]+=ps01*Q0; acc[15]+=ps01*Q1;
    acc[16]+=ps10*Q0; acc[17]+=ps10*Q1; acc[18]+=ps11*Q0; acc[19]+=ps11*Q1;
    acc[20]+=ps00; acc[21]+=ps01; acc[22]+=ps10; acc[23]+=ps11;
    v2f r0q0=r0*Q0, r1q0=r1*Q0;
    acc[24]+=r0q0*Q0; acc[25]+=r0q0*Q1; acc[26]+=r0*(Q1*Q1);
    acc[27]+=r1q0*Q0; acc[28]+=r1q0*Q1; acc[29]+=r1*(Q1*Q1);
    acc[30]+=r0q0; acc[31]+=r0*Q1; acc[32]+=r1q0; acc[33]+=r1*Q1;
    acc[34]+=r0; acc[35]+=r1;
}

__device__ __forceinline__ void bk_step2(v2f Q0, v2f Q1, v2f P0, v2f P1,
    float t1_00,float t1_01,float t1_10,float t1_11,
    float t2_00,float t2_01,float t2_10,float t2_11,float b2_0,float b2_1,
    float L1_00,float L1_01,float L1_10,float L1_11,
    float L2_00,float L2_01,float L2_10,float L2_11,float lb2_0,float lb2_1,
    v2f &B0, v2f &B1){
    v2f u0 = t2_00*Q0 + t2_01*Q1 + b2_0;
    v2f u1 = t2_10*Q0 + t2_11*Q1 + b2_1;
    v2f h0 = tanh2(u0), h1 = tanh2(u1);
    v2f s0 = 1.0f - h0*h0, s1 = 1.0f - h1*h1;
    v2f a0 = t1_00*P0 + t1_10*P1;
    v2f a1 = t1_01*P0 + t1_11*P1;
    v2f w0 = a0*s0, w1 = a1*s1;
    v2f r0 = -2.0f*(a0*h0)*s0, r1 = -2.0f*(a1*h1)*s1;
    v2f lp0 = L1_00*P0 + L1_10*P1;
    v2f lp1 = L1_01*P0 + L1_11*P1;
    v2f z0 = L2_00*Q0 + L2_01*Q1 + lb2_0;
    v2f z1 = L2_10*Q0 + L2_11*Q1 + lb2_1;
    v2f m0 = lp0*s0 + r0*z0;
    v2f m1 = lp1*s1 + r1*z1;
    B0 += t2_00*m0 + t2_10*m1 + L2_00*w0 + L2_10*w1;
    B1 += t2_01*m0 + t2_11*m1 + L2_01*w0 + L2_11*w1;
}

__global__ __launch_bounds__(TPB, 2) void k_all(
    const float4* __restrict__ q4, const float4* __restrict__ p4,
    const float4* __restrict__ x4, int nv4,
    const float* __restrict__ t1i, const float* __restrict__ b1i,
    const float* __restrict__ t2i, const float* __restrict__ b2i,
    const float* __restrict__ invK, const float* __restrict__ invKb,
    u64* __restrict__ part64,            // [36][NB] tagged partials
    u64* __restrict__ tslot64,           // [NB][12] tagged theta slots
    u64* __restrict__ pk64,              // [400] tagged pk broadcast
    float4* __restrict__ oq, float4* __restrict__ op, float4* __restrict__ ox,
    float c)
{
    const int tid  = threadIdx.x;
    const int bid  = blockIdx.x;
    const int NT   = gridDim.x * TPB;
    const int gtid = bid*TPB + tid;
    const int wave = tid >> 6, lane = tid & 63;

    __shared__ float ths[12];                  // current theta (ends as theta20)
    __shared__ float thetaAll[(NIT+1)*12];     // block0 only
    __shared__ float sAll[(NIT+1)*36];         // block0 only
    __shared__ float red[TPB/64][36];
    __shared__ float ks[16], ksb[4];
    __shared__ float4 pkS[NIT*5];              // packed theta_k + lam_{k+1}
    float* pkSf = (float*)pkS;

    if(tid < 16) ks[tid]  = 0.5f*(invK[tid]  + invK[(tid&3)*4 + (tid>>2)]);
    if(tid < 4)  ksb[tid] = 0.5f*(invKb[tid] + invKb[(tid&1)*2 + (tid>>1)]);
    if(tid < 12){
        float v = (tid<4)? t1i[tid] : (tid<6)? b1i[tid-4]
                : (tid<10)? t2i[tid-6] : b2i[tid-10];
        ths[tid] = v;
        thetaAll[tid] = v;
    }
    __syncthreads();

    // Pin this thread's samples in registers for the whole kernel.
    const bool fast = (nv4 == 4*NT);
    float4 qd[4], pd[4];
    if(fast){
        #pragma unroll
        for(int sl=0; sl<4; sl++){ qd[sl]=q4[gtid + sl*NT]; pd[sl]=p4[gtid + sl*NT]; }
    }

    for(int k=0; k<=NIT; k++){
        const float t1_00=ths[0], t1_01=ths[1], t1_10=ths[2], t1_11=ths[3];
        const float t2_00=ths[6], t2_01=ths[7], t2_10=ths[8], t2_11=ths[9];
        const float b2_0=ths[10], b2_1=ths[11];

        v2f acc[36];
        #pragma unroll
        for(int j=0;j<36;j++) acc[j] = (v2f){0.f, 0.f};

        if(fast){
            #pragma unroll
            for(int sl=0; sl<4; sl++){
                v2f Q0={qd[sl].x,qd[sl].z}, Q1={qd[sl].y,qd[sl].w};
                v2f P0={pd[sl].x,pd[sl].z}, P1={pd[sl].y,pd[sl].w};
                accum_sample2(Q0,Q1,P0,P1,
                    t1_00,t1_01,t1_10,t1_11,t2_00,t2_01,t2_10,t2_11,b2_0,b2_1,acc);
            }
        }else{
            for(int j = gtid; j < nv4; j += NT){
                float4 qq = q4[j], pp = p4[j];
                v2f Q0={qq.x,qq.z}, Q1={qq.y,qq.w};
                v2f P0={pp.x,pp.z}, P1={pp.y,pp.w};
                accum_sample2(Q0,Q1,P0,P1,
                    t1_00,t1_01,t1_10,t1_11,t2_00,t2_01,t2_10,t2_11,b2_0,b2_1,acc);
            }
        }

        // wave reduction (VALU pipe) -> block partials -> tagged u64 stores
        float wres[36];
        #pragma unroll
        for(int j=0;j<36;j++) wres[j] = wave_sum64(acc[j].x + acc[j].y);
        if(lane == 63){
            #pragma unroll
            for(int j=0;j<36;j++) red[wave][j] = wres[j];
        }
        __syncthreads();
        if(tid < 36){
            float sum = 0.f;
            #pragma unroll
            for(int w=0; w<TPB/64; w++) sum += red[w][tid];
            st64_ep(part64 + tid*NB + bid, sum, (unsigned)(k+1));  // no fence needed
        }

        if(bid == 0){
            // poll the partial DATA itself: rows {w, w+8, w+16, w+24}(+w+32 if w<4),
            // cols {lane, lane+64, lane+128, lane+192} — coalesced u64 loads.
            const unsigned tgt = (unsigned)(k+1);
            const int r4i = (wave<4)? (wave+32) : (wave+24);   // dummy repeat if wave>=4
            const u64* R0 = part64 + (size_t)(wave     )*NB;
            const u64* R1 = part64 + (size_t)(wave +  8)*NB;
            const u64* R2 = part64 + (size_t)(wave + 16)*NB;
            const u64* R3 = part64 + (size_t)(wave + 24)*NB;
            const u64* R4 = part64 + (size_t)(r4i      )*NB;
            u64 a0,a1,a2,a3, b0,b1,b2,b3, c0,c1,c2,c3, d0,d1,d2,d3, e0,e1,e2,e3;
            int guard = 0;
            for(;;){
                a0=ld64_ag(R0+lane); a1=ld64_ag(R0+lane+64); a2=ld64_ag(R0+lane+128); a3=ld64_ag(R0+lane+192);
                b0=ld64_ag(R1+lane); b1=ld64_ag(R1+lane+64); b2=ld64_ag(R1+lane+128); b3=ld64_ag(R1+lane+192);
                c0=ld64_ag(R2+lane); c1=ld64_ag(R2+lane+64); c2=ld64_ag(R2+lane+128); c3=ld64_ag(R2+lane+192);
                d0=ld64_ag(R3+lane); d1=ld64_ag(R3+lane+64); d2=ld64_ag(R3+lane+128); d3=ld64_ag(R3+lane+192);
                e0=ld64_ag(R4+lane); e1=ld64_ag(R4+lane+64); e2=ld64_ag(R4+lane+128); e3=ld64_ag(R4+lane+192);
                bool ok = ep_of(a0)>=tgt && ep_of(a1)>=tgt && ep_of(a2)>=tgt && ep_of(a3)>=tgt
                       && ep_of(b0)>=tgt && ep_of(b1)>=tgt && ep_of(b2)>=tgt && ep_of(b3)>=tgt
                       && ep_of(c0)>=tgt && ep_of(c1)>=tgt && ep_of(c2)>=tgt && ep_of(c3)>=tgt
                       && ep_of(d0)>=tgt && ep_of(d1)>=tgt && ep_of(d2)>=tgt && ep_of(d3)>=tgt
                       && ep_of(e0)>=tgt && ep_of(e1)>=tgt && ep_of(e2)>=tgt && ep_of(e3)>=tgt;
                if(__all(ok)) break;
                __builtin_amdgcn_s_sleep(1);
                if(++guard > GUARD) break;   // watchdog: wrong-answer, never hang
            }
            float s0 = wave_sum64(val_of(a0)+val_of(a1)+val_of(a2)+val_of(a3));
            float s1 = wave_sum64(val_of(b0)+val_of(b1)+val_of(b2)+val_of(b3));
            float s2 = wave_sum64(val_of(c0)+val_of(c1)+val_of(c2)+val_of(c3));
            float s3 = wave_sum64(val_of(d0)+val_of(d1)+val_of(d2)+val_of(d3));
            float s4 = wave_sum64(val_of(e0)+val_of(e1)+val_of(e2)+val_of(e3));
            if(lane == 63){
                sAll[k*36 + wave]      = s0;
                sAll[k*36 + wave + 8]  = s1;
                sAll[k*36 + wave + 16] = s2;
                sAll[k*36 + wave + 24] = s3;
                if(wave < 4) sAll[k*36 + wave + 32] = s4;
            }
            __syncthreads();
            if(tid == 0 && k < NIT){
                float g[12];
                compute_grad(sAll + k*36, thetaAll + k*12, ks, ksb, c, g);
                #pragma unroll
                for(int j=0;j<12;j++){
                    float t = thetaAll[k*12+j] - LR*g[j];
                    ths[j] = t;
                    thetaAll[(k+1)*12+j] = t;
                }
            }
            __syncthreads();
            if(k < NIT){
                // 3072 tagged u64, coalesced, 6 per thread; data==flag
                for(int f = tid; f < NB*12; f += TPB)
                    st64_ep(tslot64 + f, ths[f % 12], (unsigned)(k+1));
            }
        }else if(k < NIT){
            // readers: poll OWN 96B slot; detect == payload (same load)
            if(wave == 0){
                const unsigned tgt = (unsigned)(k+1);
                const u64* sp = tslot64 + bid*12;
                const int idx = (lane < 12)? lane : 0;
                u64 v; int guard = 0;
                for(;;){
                    v = ld64_ag(sp + idx);
                    bool ok = (lane < 12)? (ep_of(v) >= tgt) : true;
                    if(__all(ok)) break;
                    __builtin_amdgcn_s_sleep(8);     // throttle 255-block poll traffic
                    if(++guard > GUARD) break;       // watchdog
                }
                if(lane < 12) ths[lane] = val_of(v);
            }
            __syncthreads();
        }
    }

    // ---- backfold (block 0 only), then one tagged pk broadcast ----
    if(bid == 0){
        if(tid == 0){
            float lv[12];
            compute_grad(sAll + NIT*36, thetaAll + NIT*12, ks, ksb, c, lv);
            for(int k=NIT-1;k>=0;k--){
                const float* s = sAll + k*36;
                const float* T = thetaAll + k*12;
                float* P = (float*)&pkS[k*5];
                P[0]=T[0]; P[1]=T[1]; P[2]=T[2]; P[3]=T[3];
                P[4]=T[6]; P[5]=T[7]; P[6]=T[8]; P[7]=T[9];
                P[8]=T[10]; P[9]=T[11];
                P[10]=lv[0]; P[11]=lv[1]; P[12]=lv[2]; P[13]=lv[3];
                P[14]=lv[6]; P[15]=lv[7]; P[16]=lv[8]; P[17]=lv[9];
                P[18]=lv[10]; P[19]=lv[11];
                float H[12];
                for(int a=0;a<2;a++)for(int b=0;b<2;b++){
                    int j=a*2+b;
                    float data = s[12+a*4+b*2+0]*lv[6+b*2+0]
                               + s[12+a*4+b*2+1]*lv[6+b*2+1]
                               + s[20+a*2+b]*lv[10+b];
                    float kv=0.f;
                    for(int m=0;m<4;m++) kv += ks[j*4+m]*lv[m];
                    H[j]=kv - c*data;
                }
                H[4] = ksb[0]*lv[4] + ksb[1]*lv[5];
                H[5] = ksb[2]*lv[4] + ksb[3]*lv[5];
                for(int cc=0;cc<2;cc++)for(int d=0;d<2;d++){
                    int j=cc*2+d;
                    float term1 = lv[0+cc]*s[12+0*4+cc*2+d] + lv[2+cc]*s[12+1*4+cc*2+d];
                    float term2 = lv[6+cc*2+0]*s[24+cc*3+(0+d)] + lv[6+cc*2+1]*s[24+cc*3+(1+d)];
                    float term3 = lv[10+cc]*s[30+cc*2+d];
                    float kv=0.f;
                    for(int m=0;m<4;m++) kv += ks[j*4+m]*lv[6+m];
                    H[6+j]=kv - c*(term1+term2+term3);
                }
                for(int cc=0;cc<2;cc++){
                    float z1 = lv[0+cc]*s[20+0*2+cc] + lv[2+cc]*s[20+1*2+cc];
                    float z2 = lv[6+cc*2+0]*s[30+cc*2+0] + lv[6+cc*2+1]*s[30+cc*2+1];
                    float z3 = lv[10+cc]*s[34+cc];
                    float kv = ksb[cc*2+0]*lv[10] + ksb[cc*2+1]*lv[11];
                    H[10+cc]=kv - c*(z1+z2+z3);
                }
                for(int j=0;j<12;j++) lv[j] -= LR*H[j];
            }
        }
        __syncthreads();
        if(tid < NIT*20) st64_ep(pk64 + tid, pkSf[tid], (unsigned)(NIT+1));
    }else{
        if(tid < NIT*20){
            u64 v; int guard = 0;
            for(;;){
                v = ld64_ag(pk64 + tid);
                if(ep_of(v) >= (unsigned)(NIT+1)) break;
                __builtin_amdgcn_s_sleep(8);
                if(++guard > GUARD) break;   // watchdog
            }
            pkSf[tid] = val_of(v);
        }
        __syncthreads();
    }

    // final phase: ths == theta row 20; pkS in LDS; q/p still in registers
    const float f1_00=ths[0], f1_01=ths[1], f1_10=ths[2], f1_11=ths[3];
    const float fb1_0=ths[4], fb1_1=ths[5];
    const float f2_00=ths[6], f2_01=ths[7], f2_10=ths[8], f2_11=ths[9];
    const float fb2_0=ths[10], fb2_1=ths[11];

    if(fast){
        v2f Q0r[4],Q1r[4],P0r[4],P1r[4],B0r[4],B1r[4];
        #pragma unroll
        for(int sl=0; sl<4; sl++){
            Q0r[sl]=(v2f){qd[sl].x,qd[sl].z}; Q1r[sl]=(v2f){qd[sl].y,qd[sl].w};
            P0r[sl]=(v2f){pd[sl].x,pd[sl].z}; P1r[sl]=(v2f){pd[sl].y,pd[sl].w};
            B0r[sl]=(v2f){0.f,0.f}; B1r[sl]=(v2f){0.f,0.f};
        }
        for(int k=0;k<NIT;k++){
            float4 P0=pkS[k*5+0], P1=pkS[k*5+1], P2=pkS[k*5+2], P3=pkS[k*5+3], P4v=pkS[k*5+4];
            float t1_00=P0.x,t1_01=P0.y,t1_10=P0.z,t1_11=P0.w;
            float t2_00=P1.x,t2_01=P1.y,t2_10=P1.z,t2_11=P1.w;
            float b2_0=P2.x,b2_1=P2.y;
            float L1_00=P2.z,L1_01=P2.w,L1_10=P3.x,L1_11=P3.y;
            float L2_00=P3.z,L2_01=P3.w,L2_10=P4v.x,L2_11=P4v.y,lb2_0=P4v.z,lb2_1=P4v.w;
            #pragma unroll
            for(int sl=0; sl<4; sl++)
                bk_step2(Q0r[sl],Q1r[sl],P0r[sl],P1r[sl],
                    t1_00,t1_01,t1_10,t1_11,t2_00,t2_01,t2_10,t2_11,b2_0,b2_1,
                    L1_00,L1_01,L1_10,L1_11,L2_00,L2_01,L2_10,L2_11,lb2_0,lb2_1,
                    B0r[sl],B1r[sl]);
        }
        #pragma unroll
        for(int sl=0; sl<4; sl++){
            int j = gtid + sl*NT;
            v2f Q0=Q0r[sl], Q1=Q1r[sl], P0=P0r[sl], P1=P1r[sl];
            v2f Bs0=B0r[sl], Bs1=B1r[sl];
            v2f u0 = f2_00*Q0 + f2_01*Q1 + fb2_0;
            v2f u1 = f2_10*Q0 + f2_11*Q1 + fb2_1;
            v2f h0 = tanh2(u0), h1 = tanh2(u1);
            v2f s0 = 1.0f - h0*h0, s1 = 1.0f - h1*h1;
            v2f a0 = f1_00*P0 + f1_10*P1;
            v2f a1 = f1_01*P0 + f1_11*P1;
            v2f w0 = a0*s0, w1 = a1*s1;
            v2f dq0 = f1_00*h0 + f1_01*h1 + fb1_0;
            v2f dq1 = f1_10*h0 + f1_11*h1 + fb1_1;
            v2f dp0 = c*(LR*Bs0 - (f2_00*w0 + f2_10*w1));
            v2f dp1 = c*(LR*Bs1 - (f2_01*w0 + f2_11*w1));
            oq[j] = make_float4(dq0.x, dq1.x, dq0.y, dq1.y);
            op[j] = make_float4(dp0.x, dp1.x, dp0.y, dp1.y);
            float4 xx = x4[j];
            v2f X0={xx.x,xx.z}, X1={xx.y,xx.w};
            v2f xu0 = f2_00*X0 + f2_01*X1 + fb2_0;
            v2f xu1 = f2_10*X0 + f2_11*X1 + fb2_1;
            v2f xh0 = tanh2(xu0), xh1 = tanh2(xu1);
            v2f xd0 = f1_00*xh0 + f1_01*xh1 + fb1_0;
            v2f xd1 = f1_10*xh0 + f1_11*xh1 + fb1_1;
            ox[j] = make_float4(xd0.x, xd1.x, xd0.y, xd1.y);
        }
    }else{
        for(int j = gtid; j < nv4; j += NT){
            float4 qq=q4[j], pp=p4[j];
            v2f Q0={qq.x,qq.z}, Q1={qq.y,qq.w};
            v2f P0={pp.x,pp.z}, P1={pp.y,pp.w};
            v2f Bs0={0.f,0.f}, Bs1={0.f,0.f};
            for(int k=0;k<NIT;k++){
                float4 P0v=pkS[k*5+0], P1v=pkS[k*5+1], P2v=pkS[k*5+2], P3v=pkS[k*5+3], P4v=pkS[k*5+4];
                bk_step2(Q0,Q1,P0,P1,
                    P0v.x,P0v.y,P0v.z,P0v.w, P1v.x,P1v.y,P1v.z,P1v.w, P2v.x,P2v.y,
                    P2v.z,P2v.w,P3v.x,P3v.y, P3v.z,P3v.w,P4v.x,P4v.y,P4v.z,P4v.w,
                    Bs0,Bs1);
            }
            v2f u0 = f2_00*Q0 + f2_01*Q1 + fb2_0;
            v2f u1 = f2_10*Q0 + f2_11*Q1 + fb2_1;
            v2f h0 = tanh2(u0), h1 = tanh2(u1);
            v2f s0 = 1.0f - h0*h0, s1 = 1.0f - h1*h1;
            v2f a0 = f1_00*P0 + f1_10*P1;
            v2f a1 = f1_01*P0 + f1_11*P1;
            v2f w0 = a0*s0, w1 = a1*s1;
            v2f dq0 = f1_00*h0 + f1_01*h1 + fb1_0;
            v2f dq1 = f1_10*h0 + f1_11*h1 + fb1_1;
            v2f dp0 = c*(LR*Bs0 - (f2_00*w0 + f2_10*w1));
            v2f dp1 = c*(LR*Bs1 - (f2_01*w0 + f2_11*w1));
            oq[j] = make_float4(dq0.x, dq1.x, dq0.y, dq1.y);
            op[j] = make_float4(dp0.x, dp1.x, dp0.y, dp1.y);
            float4 xx = x4[j];
            v2f X0={xx.x,xx.z}, X1={xx.y,xx.w};
            v2f xu0 = f2_00*X0 + f2_01*X1 + fb2_0;
            v2f xu1 = f2_10*X0 + f2_11*X1 + fb2_1;
            v2f xh0 = tanh2(xu0), xh1 = tanh2(xu1);
            v2f xd0 = f1_00*xh0 + f1_01*xh1 + fb1_0;
            v2f xd1 = f1_10*xh0 + f1_11*xh1 + fb1_1;
            ox[j] = make_float4(xd0.x, xd1.x, xd0.y, xd1.y);
        }
    }
}

extern "C" void kernel_launch(void* const* d_in, const int* in_sizes, int n_in,
                              void* d_out, int out_size, void* d_ws, size_t ws_size,
                              hipStream_t stream) {
    const float* inp = (const float*)d_in[1];
    const int K = in_sizes[1]/6;
    int nv4 = K >> 1;

    const float4* q4 = (const float4*)inp;
    const float4* p4 = (const float4*)(inp + 2*(size_t)K);
    const float4* x4 = (const float4*)(inp + 4*(size_t)K);

    u64* part64  = (u64*)d_ws;                 // [36*NB]
    u64* tslot64 = part64 + 36*NB;             // [NB*12]
    u64* pk64    = tslot64 + NB*12;            // [400]
    float c = 1.0f/(2.0f*(float)K);

    const float* t1i = (const float*)d_in[2];
    const float* b1i = (const float*)d_in[3];
    const float* t2i = (const float*)d_in[4];
    const float* b2i = (const float*)d_in[5];
    const float* invK = (const float*)d_in[6];
    const float* invKb= (const float*)d_in[7];

    float* out = (float*)d_out;
    float4* oq = (float4*)out;
    float4* op = (float4*)(out + 2*(size_t)K);
    float4* ox = (float4*)(out + 4*(size_t)K);

    // zero all epoch-bearing words (epochs restart at 0 every launch)
    size_t zb = (size_t)(36*NB + NB*12 + 400)*sizeof(u64);
    hipMemsetAsync(d_ws, 0, zb, stream);
    k_all<<<dim3(NB), dim3(TPB), 0, stream>>>(q4, p4, x4, nv4,
                                              t1i, b1i, t2i, b2i, invK, invKb,
                                              part64, tslot64, pk64, oq, op, ox, c);
}

// Round 9
// 254.732 us; speedup vs baseline: 2.1812x; 1.0271x over previous
//
#include <hip/hip_runtime.h>

// ShootingBlockMNModel1 — single fused kernel, regular launch (graph-safe).
// r7 structure (known-good) + final-phase overlap + coalesced pk poll.
// Epoch-tagged u64 protocol: every shared datum is one atomic {f32,epoch}
// word — data is its own flag (no fences, no drains, no flag/payload split).
//   workers: 36 tagged partials; poll OWN 96B theta slot (detect==payload).
//   block 0 (dual role): worker duties + poll partial DATA coalesced,
//     grad, broadcast tagged theta slots; then backfold + pk broadcast.
//   final phase: oq/ox written BEFORE pk poll (overlaps block0's backfold),
//     then wave0 polls pk coalesced (7 u64/lane -> LDS), then B loop + op.
// s_sleep backoff on all polls (r6 lesson: busy-spin saturates the MALL).
// q/p pinned in VGPRs across the whole kernel (loaded once).
//
// ws (u64): part64[36*NB] ; tslot64[NB*12] ; pk64[400]  (memset ~100KB)

#define LR 0.25f
#define NIT 20
#define TPB 512
#define NB  256
#define GUARD (1<<20)

typedef float v2f __attribute__((ext_vector_type(2)));
typedef unsigned long long u64;

__device__ __forceinline__ u64 ld64_ag(const u64* p){
    return __hip_atomic_load(p, __ATOMIC_RELAXED, __HIP_MEMORY_SCOPE_AGENT);
}
__device__ __forceinline__ void st64_ep(u64* p, float v, unsigned ep){
    u64 x = ((u64)ep << 32) | (u64)__float_as_uint(v);
    __hip_atomic_store(p, x, __ATOMIC_RELAXED, __HIP_MEMORY_SCOPE_AGENT);
}
__device__ __forceinline__ unsigned ep_of(u64 x){ return (unsigned)(x >> 32); }
__device__ __forceinline__ float    val_of(u64 x){ return __uint_as_float((unsigned)(x & 0xffffffffull)); }

__device__ __forceinline__ v2f tanh2(v2f x){
    v2f e;
    e.x = __expf(x.x + x.x);
    e.y = __expf(x.y + x.y);
    v2f d = e + 1.0f;
    v2f r;
    r.x = __builtin_amdgcn_rcpf(d.x);
    r.y = __builtin_amdgcn_rcpf(d.y);
    return 1.0f - (r + r);
}

// wave64 sum via DPP on the VALU pipe; result valid in lane 63
#define DPP_ADD(x, ctrl) ((x) + __int_as_float(__builtin_amdgcn_update_dpp(0, __float_as_int(x), (ctrl), 0xF, 0xF, true)))
__device__ __forceinline__ float wave_sum64(float x){
    x = DPP_ADD(x, 0x111);   // row_shr:1
    x = DPP_ADD(x, 0x112);   // row_shr:2
    x = DPP_ADD(x, 0x114);   // row_shr:4
    x = DPP_ADD(x, 0x118);   // row_shr:8  -> lane 15+16r = row sum
    x = DPP_ADD(x, 0x142);   // row_bcast:15
    x = DPP_ADD(x, 0x143);   // row_bcast:31 -> lane 63 = total
    return x;
}

__device__ __forceinline__ void compute_grad(const float* s, const float* th,
                                             const float* ksym, const float* ksymb,
                                             float c, float* g){
    const float Ivec[4]={1.f,0.f,0.f,1.f};
    #pragma unroll
    for(int j=0;j<4;j++){
        float kv=0.f;
        #pragma unroll
        for(int m=0;m<4;m++) kv += ksym[j*4+m]*th[m];
        g[j] = kv - c*s[j];
    }
    #pragma unroll
    for(int i2=0;i2<2;i2++)
        g[4+i2] = ksymb[i2*2+0]*th[4] + ksymb[i2*2+1]*th[5] - c*s[4+i2];
    #pragma unroll
    for(int j=0;j<4;j++){
        float kv=0.f;
        #pragma unroll
        for(int m=0;m<4;m++) kv += ksym[j*4+m]*(th[6+m]-Ivec[m]);
        g[6+j] = kv - c*s[6+j];
    }
    #pragma unroll
    for(int i2=0;i2<2;i2++)
        g[10+i2] = ksymb[i2*2+0]*th[10] + ksymb[i2*2+1]*th[11] - c*s[10+i2];
}

// packed accumulate: float4 = 2 samples in v2f lanes
__device__ __forceinline__ void accum_sample2(v2f Q0, v2f Q1, v2f P0, v2f P1,
    float t1_00,float t1_01,float t1_10,float t1_11,
    float t2_00,float t2_01,float t2_10,float t2_11,float b2_0,float b2_1,
    v2f (&acc)[36]){
    v2f u0 = t2_00*Q0 + t2_01*Q1 + b2_0;
    v2f u1 = t2_10*Q0 + t2_11*Q1 + b2_1;
    v2f h0 = tanh2(u0), h1 = tanh2(u1);
    v2f s0 = 1.0f - h0*h0, s1 = 1.0f - h1*h1;
    v2f a0 = t1_00*P0 + t1_10*P1;
    v2f a1 = t1_01*P0 + t1_11*P1;
    v2f w0 = a0*s0, w1 = a1*s1;
    v2f r0 = -2.0f*(a0*h0)*s0, r1 = -2.0f*(a1*h1)*s1;
    acc[0]+=P0*h0; acc[1]+=P0*h1; acc[2]+=P1*h0; acc[3]+=P1*h1;
    acc[4]+=P0;    acc[5]+=P1;
    acc[6]+=w0*Q0; acc[7]+=w0*Q1; acc[8]+=w1*Q0; acc[9]+=w1*Q1;
    acc[10]+=w0;   acc[11]+=w1;
    v2f ps00=P0*s0, ps01=P0*s1, ps10=P1*s0, ps11=P1*s1;
    acc[12]+=ps00*Q0; acc[13]+=ps00*Q1; acc[14]+=ps01*Q0; acc[15]+=ps01*Q1;
    acc[16]+=ps10*Q0; acc[17]+=ps10*Q1; acc[18]+=ps11*Q0; acc[19]+=ps11*Q1;
    acc[20]+=ps00; acc[21]+=ps01; acc[22]+=ps10; acc[23]+=ps11;
    v2f r0q0=r0*Q0, r1q0=r1*Q0;
    acc[24]+=r0q0*Q0; acc[25]+=r0q0*Q1; acc[26]+=r0*(Q1*Q1);
    acc[27]+=r1q0*Q0; acc[28]+=r1q0*Q1; acc[29]+=r1*(Q1*Q1);
    acc[30]+=r0q0; acc[31]+=r0*Q1; acc[32]+=r1q0; acc[33]+=r1*Q1;
    acc[34]+=r0; acc[35]+=r1;
}

__device__ __forceinline__ void bk_step2(v2f Q0, v2f Q1, v2f P0, v2f P1,
    float t1_00,float t1_01,float t1_10,float t1_11,
    float t2_00,float t2_01,float t2_10,float t2_11,float b2_0,float b2_1,
    float L1_00,float L1_01,float L1_10,float L1_11,
    float L2_00,float L2_01,float L2_10,float L2_11,float lb2_0,float lb2_1,
    v2f &B0, v2f &B1){
    v2f u0 = t2_00*Q0 + t2_01*Q1 + b2_0;
    v2f u1 = t2_10*Q0 + t2_11*Q1 + b2_1;
    v2f h0 = tanh2(u0), h1 = tanh2(u1);
    v2f s0 = 1.0f - h0*h0, s1 = 1.0f - h1*h1;
    v2f a0 = t1_00*P0 + t1_10*P1;
    v2f a1 = t1_01*P0 + t1_11*P1;
    v2f w0 = a0*s0, w1 = a1*s1;
    v2f r0 = -2.0f*(a0*h0)*s0, r1 = -2.0f*(a1*h1)*s1;
    v2f lp0 = L1_00*P0 + L1_10*P1;
    v2f lp1 = L1_01*P0 + L1_11*P1;
    v2f z0 = L2_00*Q0 + L2_01*Q1 + lb2_0;
    v2f z1 = L2_10*Q0 + L2_11*Q1 + lb2_1;
    v2f m0 = lp0*s0 + r0*z0;
    v2f m1 = lp1*s1 + r1*z1;
    B0 += t2_00*m0 + t2_10*m1 + L2_00*w0 + L2_10*w1;
    B1 += t2_01*m0 + t2_11*m1 + L2_01*w0 + L2_11*w1;
}

__global__ __launch_bounds__(TPB, 2) void k_all(
    const float4* __restrict__ q4, const float4* __restrict__ p4,
    const float4* __restrict__ x4, int nv4,
    const float* __restrict__ t1i, const float* __restrict__ b1i,
    const float* __restrict__ t2i, const float* __restrict__ b2i,
    const float* __restrict__ invK, const float* __restrict__ invKb,
    u64* __restrict__ part64,            // [36][NB] tagged partials
    u64* __restrict__ tslot64,           // [NB][12] tagged theta slots
    u64* __restrict__ pk64,              // [400] tagged pk broadcast
    float4* __restrict__ oq, float4* __restrict__ op, float4* __restrict__ ox,
    float c)
{
    const int tid  = threadIdx.x;
    const int bid  = blockIdx.x;
    const int NT   = gridDim.x * TPB;
    const int gtid = bid*TPB + tid;
    const int wave = tid >> 6, lane = tid & 63;

    __shared__ float ths[12];                  // current theta (ends as theta20)
    __shared__ float thetaAll[(NIT+1)*12];     // block0 only
    __shared__ float sAll[(NIT+1)*36];         // block0 only
    __shared__ float red[TPB/64][36];
    __shared__ float ks[16], ksb[4];
    __shared__ float4 pkS[NIT*5];              // packed theta_k + lam_{k+1}
    float* pkSf = (float*)pkS;

    if(tid < 16) ks[tid]  = 0.5f*(invK[tid]  + invK[(tid&3)*4 + (tid>>2)]);
    if(tid < 4)  ksb[tid] = 0.5f*(invKb[tid] + invKb[(tid&1)*2 + (tid>>1)]);
    if(tid < 12){
        float v = (tid<4)? t1i[tid] : (tid<6)? b1i[tid-4]
                : (tid<10)? t2i[tid-6] : b2i[tid-10];
        ths[tid] = v;
        thetaAll[tid] = v;
    }
    __syncthreads();

    // Pin this thread's samples in registers for the whole kernel.
    const bool fast = (nv4 == 4*NT);
    float4 qd[4], pd[4];
    if(fast){
        #pragma unroll
        for(int sl=0; sl<4; sl++){ qd[sl]=q4[gtid + sl*NT]; pd[sl]=p4[gtid + sl*NT]; }
    }

    for(int k=0; k<=NIT; k++){
        const float t1_00=ths[0], t1_01=ths[1], t1_10=ths[2], t1_11=ths[3];
        const float t2_00=ths[6], t2_01=ths[7], t2_10=ths[8], t2_11=ths[9];
        const float b2_0=ths[10], b2_1=ths[11];

        v2f acc[36];
        #pragma unroll
        for(int j=0;j<36;j++) acc[j] = (v2f){0.f, 0.f};

        if(fast){
            #pragma unroll
            for(int sl=0; sl<4; sl++){
                v2f Q0={qd[sl].x,qd[sl].z}, Q1={qd[sl].y,qd[sl].w};
                v2f P0={pd[sl].x,pd[sl].z}, P1={pd[sl].y,pd[sl].w};
                accum_sample2(Q0,Q1,P0,P1,
                    t1_00,t1_01,t1_10,t1_11,t2_00,t2_01,t2_10,t2_11,b2_0,b2_1,acc);
            }
        }else{
            for(int j = gtid; j < nv4; j += NT){
                float4 qq = q4[j], pp = p4[j];
                v2f Q0={qq.x,qq.z}, Q1={qq.y,qq.w};
                v2f P0={pp.x,pp.z}, P1={pp.y,pp.w};
                accum_sample2(Q0,Q1,P0,P1,
                    t1_00,t1_01,t1_10,t1_11,t2_00,t2_01,t2_10,t2_11,b2_0,b2_1,acc);
            }
        }

        // wave reduction (VALU pipe) -> block partials -> tagged u64 stores
        float wres[36];
        #pragma unroll
        for(int j=0;j<36;j++) wres[j] = wave_sum64(acc[j].x + acc[j].y);
        if(lane == 63){
            #pragma unroll
            for(int j=0;j<36;j++) red[wave][j] = wres[j];
        }
        __syncthreads();
        if(tid < 36){
            float sum = 0.f;
            #pragma unroll
            for(int w=0; w<TPB/64; w++) sum += red[w][tid];
            st64_ep(part64 + tid*NB + bid, sum, (unsigned)(k+1));  // no fence needed
        }

        if(bid == 0){
            // poll the partial DATA itself: rows {w, w+8, w+16, w+24}(+w+32 if w<4),
            // cols {lane, lane+64, lane+128, lane+192} — coalesced u64 loads.
            const unsigned tgt = (unsigned)(k+1);
            const int r4i = (wave<4)? (wave+32) : (wave+24);   // dummy repeat if wave>=4
            const u64* R0 = part64 + (size_t)(wave     )*NB;
            const u64* R1 = part64 + (size_t)(wave +  8)*NB;
            const u64* R2 = part64 + (size_t)(wave + 16)*NB;
            const u64* R3 = part64 + (size_t)(wave + 24)*NB;
            const u64* R4 = part64 + (size_t)(r4i      )*NB;
            u64 a0,a1,a2,a3, b0,b1,b2,b3, c0,c1,c2,c3, d0,d1,d2,d3, e0,e1,e2,e3;
            int guard = 0;
            for(;;){
                a0=ld64_ag(R0+lane); a1=ld64_ag(R0+lane+64); a2=ld64_ag(R0+lane+128); a3=ld64_ag(R0+lane+192);
                b0=ld64_ag(R1+lane); b1=ld64_ag(R1+lane+64); b2=ld64_ag(R1+lane+128); b3=ld64_ag(R1+lane+192);
                c0=ld64_ag(R2+lane); c1=ld64_ag(R2+lane+64); c2=ld64_ag(R2+lane+128); c3=ld64_ag(R2+lane+192);
                d0=ld64_ag(R3+lane); d1=ld64_ag(R3+lane+64); d2=ld64_ag(R3+lane+128); d3=ld64_ag(R3+lane+192);
                e0=ld64_ag(R4+lane); e1=ld64_ag(R4+lane+64); e2=ld64_ag(R4+lane+128); e3=ld64_ag(R4+lane+192);
                bool ok = ep_of(a0)>=tgt && ep_of(a1)>=tgt && ep_of(a2)>=tgt && ep_of(a3)>=tgt
                       && ep_of(b0)>=tgt && ep_of(b1)>=tgt && ep_of(b2)>=tgt && ep_of(b3)>=tgt
                       && ep_of(c0)>=tgt && ep_of(c1)>=tgt && ep_of(c2)>=tgt && ep_of(c3)>=tgt
                       && ep_of(d0)>=tgt && ep_of(d1)>=tgt && ep_of(d2)>=tgt && ep_of(d3)>=tgt
                       && ep_of(e0)>=tgt && ep_of(e1)>=tgt && ep_of(e2)>=tgt && ep_of(e3)>=tgt;
                if(__all(ok)) break;
                __builtin_amdgcn_s_sleep(1);
                if(++guard > GUARD) break;   // watchdog: wrong-answer, never hang
            }
            float s0 = wave_sum64(val_of(a0)+val_of(a1)+val_of(a2)+val_of(a3));
            float s1 = wave_sum64(val_of(b0)+val_of(b1)+val_of(b2)+val_of(b3));
            float s2 = wave_sum64(val_of(c0)+val_of(c1)+val_of(c2)+val_of(c3));
            float s3 = wave_sum64(val_of(d0)+val_of(d1)+val_of(d2)+val_of(d3));
            float s4 = wave_sum64(val_of(e0)+val_of(e1)+val_of(e2)+val_of(e3));
            if(lane == 63){
                sAll[k*36 + wave]      = s0;
                sAll[k*36 + wave + 8]  = s1;
                sAll[k*36 + wave + 16] = s2;
                sAll[k*36 + wave + 24] = s3;
                if(wave < 4) sAll[k*36 + wave + 32] = s4;
            }
            __syncthreads();
            if(tid == 0 && k < NIT){
                float g[12];
                compute_grad(sAll + k*36, thetaAll + k*12, ks, ksb, c, g);
                #pragma unroll
                for(int j=0;j<12;j++){
                    float t = thetaAll[k*12+j] - LR*g[j];
                    ths[j] = t;
                    thetaAll[(k+1)*12+j] = t;
                }
            }
            __syncthreads();
            if(k < NIT){
                // 3072 tagged u64, coalesced, 6 per thread; data==flag
                for(int f = tid; f < NB*12; f += TPB)
                    st64_ep(tslot64 + f, ths[f % 12], (unsigned)(k+1));
            }
        }else if(k < NIT){
            // readers: poll OWN 96B slot; detect == payload (same load)
            if(wave == 0){
                const unsigned tgt = (unsigned)(k+1);
                const u64* sp = tslot64 + bid*12;
                const int idx = (lane < 12)? lane : 0;
                u64 v; int guard = 0;
                for(;;){
                    v = ld64_ag(sp + idx);
                    bool ok = (lane < 12)? (ep_of(v) >= tgt) : true;
                    if(__all(ok)) break;
                    __builtin_amdgcn_s_sleep(2);     // private line: light traffic
                    if(++guard > GUARD) break;       // watchdog
                }
                if(lane < 12) ths[lane] = val_of(v);
            }
            __syncthreads();
        }
    }

    // ---- backfold (block 0 only), then one tagged pk broadcast ----
    if(bid == 0){
        if(tid == 0){
            float lv[12];
            compute_grad(sAll + NIT*36, thetaAll + NIT*12, ks, ksb, c, lv);
            for(int k=NIT-1;k>=0;k--){
                const float* s = sAll + k*36;
                const float* T = thetaAll + k*12;
                float* P = (float*)&pkS[k*5];
                P[0]=T[0]; P[1]=T[1]; P[2]=T[2]; P[3]=T[3];
                P[4]=T[6]; P[5]=T[7]; P[6]=T[8]; P[7]=T[9];
                P[8]=T[10]; P[9]=T[11];
                P[10]=lv[0]; P[11]=lv[1]; P[12]=lv[2]; P[13]=lv[3];
                P[14]=lv[6]; P[15]=lv[7]; P[16]=lv[8]; P[17]=lv[9];
                P[18]=lv[10]; P[19]=lv[11];
                float H[12];
                for(int a=0;a<2;a++)for(int b=0;b<2;b++){
                    int j=a*2+b;
                    float data = s[12+a*4+b*2+0]*lv[6+b*2+0]
                               + s[12+a*4+b*2+1]*lv[6+b*2+1]
                               + s[20+a*2+b]*lv[10+b];
                    float kv=0.f;
                    for(int m=0;m<4;m++) kv += ks[j*4+m]*lv[m];
                    H[j]=kv - c*data;
                }
                H[4] = ksb[0]*lv[4] + ksb[1]*lv[5];
                H[5] = ksb[2]*lv[4] + ksb[3]*lv[5];
                for(int cc=0;cc<2;cc++)for(int d=0;d<2;d++){
                    int j=cc*2+d;
                    float term1 = lv[0+cc]*s[12+0*4+cc*2+d] + lv[2+cc]*s[12+1*4+cc*2+d];
                    float term2 = lv[6+cc*2+0]*s[24+cc*3+(0+d)] + lv[6+cc*2+1]*s[24+cc*3+(1+d)];
                    float term3 = lv[10+cc]*s[30+cc*2+d];
                    float kv=0.f;
                    for(int m=0;m<4;m++) kv += ks[j*4+m]*lv[6+m];
                    H[6+j]=kv - c*(term1+term2+term3);
                }
                for(int cc=0;cc<2;cc++){
                    float z1 = lv[0+cc]*s[20+0*2+cc] + lv[2+cc]*s[20+1*2+cc];
                    float z2 = lv[6+cc*2+0]*s[30+cc*2+0] + lv[6+cc*2+1]*s[30+cc*2+1];
                    float z3 = lv[10+cc]*s[34+cc];
                    float kv = ksb[cc*2+0]*lv[10] + ksb[cc*2+1]*lv[11];
                    H[10+cc]=kv - c*(z1+z2+z3);
                }
                for(int j=0;j<12;j++) lv[j] -= LR*H[j];
            }
        }
        __syncthreads();
        if(tid < NIT*20) st64_ep(pk64 + tid, pkSf[tid], (unsigned)(NIT+1));
    }

    // ---- final phase: ths == theta row 20; q/p still in registers ----
    const float f1_00=ths[0], f1_01=ths[1], f1_10=ths[2], f1_11=ths[3];
    const float fb1_0=ths[4], fb1_1=ths[5];
    const float f2_00=ths[6], f2_01=ths[7], f2_10=ths[8], f2_11=ths[9];
    const float fb2_0=ths[10], fb2_1=ths[11];

    if(fast){
        // 1) oq + ox now — overlaps block0's backfold + pk broadcast
        #pragma unroll
        for(int sl=0; sl<4; sl++){
            int j = gtid + sl*NT;
            v2f Q0={qd[sl].x,qd[sl].z}, Q1={qd[sl].y,qd[sl].w};
            v2f u0 = f2_00*Q0 + f2_01*Q1 + fb2_0;
            v2f u1 = f2_10*Q0 + f2_11*Q1 + fb2_1;
            v2f h0 = tanh2(u0), h1 = tanh2(u1);
            v2f dq0 = f1_00*h0 + f1_01*h1 + fb1_0;
            v2f dq1 = f1_10*h0 + f1_11*h1 + fb1_1;
            oq[j] = make_float4(dq0.x, dq1.x, dq0.y, dq1.y);
            float4 xx = x4[j];
            v2f X0={xx.x,xx.z}, X1={xx.y,xx.w};
            v2f xu0 = f2_00*X0 + f2_01*X1 + fb2_0;
            v2f xu1 = f2_10*X0 + f2_11*X1 + fb2_1;
            v2f xh0 = tanh2(xu0), xh1 = tanh2(xu1);
            v2f xd0 = f1_00*xh0 + f1_01*xh1 + fb1_0;
            v2f xd1 = f1_10*xh0 + f1_11*xh1 + fb1_1;
            ox[j] = make_float4(xd0.x, xd1.x, xd0.y, xd1.y);
        }
        // 2) non-block0: wave0 polls pk coalesced (7 u64/lane); payload -> LDS
        if(bid != 0){
            if(wave == 0){
                const unsigned tgt = (unsigned)(NIT+1);
                u64 v[7]; int guard = 0;
                for(;;){
                    bool ok = true;
                    #pragma unroll
                    for(int i=0;i<7;i++){
                        int idx = lane + i*64;
                        if(idx < NIT*20){
                            v[i] = ld64_ag(pk64 + idx);
                            ok = ok && (ep_of(v[i]) >= tgt);
                        }
                    }
                    if(__all(ok)) break;
                    __builtin_amdgcn_s_sleep(4);
                    if(++guard > GUARD) break;   // watchdog
                }
                #pragma unroll
                for(int i=0;i<7;i++){
                    int idx = lane + i*64;
                    if(idx < NIT*20) pkSf[idx] = val_of(v[i]);
                }
            }
            __syncthreads();
        }
        // 3) backward accumulation + op
        v2f B0r[4],B1r[4];
        #pragma unroll
        for(int sl=0; sl<4; sl++){ B0r[sl]=(v2f){0.f,0.f}; B1r[sl]=(v2f){0.f,0.f}; }
        for(int k=0;k<NIT;k++){
            float4 P0=pkS[k*5+0], P1=pkS[k*5+1], P2=pkS[k*5+2], P3=pkS[k*5+3], P4v=pkS[k*5+4];
            float t1_00=P0.x,t1_01=P0.y,t1_10=P0.z,t1_11=P0.w;
            float t2_00=P1.x,t2_01=P1.y,t2_10=P1.z,t2_11=P1.w;
            float b2_0=P2.x,b2_1=P2.y;
            float L1_00=P2.z,L1_01=P2.w,L1_10=P3.x,L1_11=P3.y;
            float L2_00=P3.z,L2_01=P3.w,L2_10=P4v.x,L2_11=P4v.y,lb2_0=P4v.z,lb2_1=P4v.w;
            #pragma unroll
            for(int sl=0; sl<4; sl++){
                v2f Q0={qd[sl].x,qd[sl].z}, Q1={qd[sl].y,qd[sl].w};
                v2f P0s={pd[sl].x,pd[sl].z}, P1s={pd[sl].y,pd[sl].w};
                bk_step2(Q0,Q1,P0s,P1s,
                    t1_00,t1_01,t1_10,t1_11,t2_00,t2_01,t2_10,t2_11,b2_0,b2_1,
                    L1_00,L1_01,L1_10,L1_11,L2_00,L2_01,L2_10,L2_11,lb2_0,lb2_1,
                    B0r[sl],B1r[sl]);
            }
        }
        #pragma unroll
        for(int sl=0; sl<4; sl++){
            int j = gtid + sl*NT;
            v2f Q0={qd[sl].x,qd[sl].z}, Q1={qd[sl].y,qd[sl].w};
            v2f P0={pd[sl].x,pd[sl].z}, P1={pd[sl].y,pd[sl].w};
            v2f u0 = f2_00*Q0 + f2_01*Q1 + fb2_0;
            v2f u1 = f2_10*Q0 + f2_11*Q1 + fb2_1;
            v2f h0 = tanh2(u0), h1 = tanh2(u1);
            v2f s0 = 1.0f - h0*h0, s1 = 1.0f - h1*h1;
            v2f a0 = f1_00*P0 + f1_10*P1;
            v2f a1 = f1_01*P0 + f1_11*P1;
            v2f w0 = a0*s0, w1 = a1*s1;
            v2f dp0 = c*(LR*B0r[sl] - (f2_00*w0 + f2_10*w1));
            v2f dp1 = c*(LR*B1r[sl] - (f2_01*w0 + f2_11*w1));
            op[j] = make_float4(dp0.x, dp1.x, dp0.y, dp1.y);
        }
    }else{
        // fallback: oq/ox pass, then poll pk, then op pass
        for(int j = gtid; j < nv4; j += NT){
            float4 qq=q4[j];
            v2f Q0={qq.x,qq.z}, Q1={qq.y,qq.w};
            v2f u0 = f2_00*Q0 + f2_01*Q1 + fb2_0;
            v2f u1 = f2_10*Q0 + f2_11*Q1 + fb2_1;
            v2f h0 = tanh2(u0), h1 = tanh2(u1);
            v2f dq0 = f1_00*h0 + f1_01*h1 + fb1_0;
            v2f dq1 = f1_10*h0 + f1_11*h1 + fb1_1;
            oq[j] = make_float4(dq0.x, dq1.x, dq0.y, dq1.y);
            float4 xx = x4[j];
            v2f X0={xx.x,xx.z}, X1={xx.y,xx.w};
            v2f xu0 = f2_00*X0 + f2_01*X1 + fb2_0;
            v2f xu1 = f2_10*X0 + f2_11*X1 + fb2_1;
            v2f xh0 = tanh2(xu0), xh1 = tanh2(xu1);
            v2f xd0 = f1_00*xh0 + f1_01*xh1 + fb1_0;
            v2f xd1 = f1_10*xh0 + f1_11*xh1 + fb1_1;
            ox[j] = make_float4(xd0.x, xd1.x, xd0.y, xd1.y);
        }
        if(bid != 0){
            if(wave == 0){
                const unsigned tgt = (unsigned)(NIT+1);
                u64 v[7]; int guard = 0;
                for(;;){
                    bool ok = true;
                    #pragma unroll
                    for(int i=0;i<7;i++){
                        int idx = lane + i*64;
                        if(idx < NIT*20){
                            v[i] = ld64_ag(pk64 + idx);
                            ok = ok && (ep_of(v[i]) >= tgt);
                        }
                    }
                    if(__all(ok)) break;
                    __builtin_amdgcn_s_sleep(4);
                    if(++guard > GUARD) break;   // watchdog
                }
                #pragma unroll
                for(int i=0;i<7;i++){
                    int idx = lane + i*64;
                    if(idx < NIT*20) pkSf[idx] = val_of(v[i]);
                }
            }
            __syncthreads();
        }
        for(int j = gtid; j < nv4; j += NT){
            float4 qq=q4[j], pp=p4[j];
            v2f Q0={qq.x,qq.z}, Q1={qq.y,qq.w};
            v2f P0={pp.x,pp.z}, P1={pp.y,pp.w};
            v2f Bs0={0.f,0.f}, Bs1={0.f,0.f};
            for(int k=0;k<NIT;k++){
                float4 P0v=pkS[k*5+0], P1v=pkS[k*5+1], P2v=pkS[k*5+2], P3v=pkS[k*5+3], P4v=pkS[k*5+4];
                bk_step2(Q0,Q1,P0,P1,
                    P0v.x,P0v.y,P0v.z,P0v.w, P1v.x,P1v.y,P1v.z,P1v.w, P2v.x,P2v.y,
                    P2v.z,P2v.w,P3v.x,P3v.y, P3v.z,P3v.w,P4v.x,P4v.y,P4v.z,P4v.w,
                    Bs0,Bs1);
            }
            v2f u0 = f2_00*Q0 + f2_01*Q1 + fb2_0;
            v2f u1 = f2_10*Q0 + f2_11*Q1 + fb2_1;
            v2f h0 = tanh2(u0), h1 = tanh2(u1);
            v2f s0 = 1.0f - h0*h0, s1 = 1.0f - h1*h1;
            v2f a0 = f1_00*P0 + f1_10*P1;
            v2f a1 = f1_01*P0 + f1_11*P1;
            v2f w0 = a0*s0, w1 = a1*s1;
            v2f dp0 = c*(LR*Bs0 - (f2_00*w0 + f2_10*w1));
            v2f dp1 = c*(LR*Bs1 - (f2_01*w0 + f2_11*w1));
            op[j] = make_float4(dp0.x, dp1.x, dp0.y, dp1.y);
        }
    }
}

extern "C" void kernel_launch(void* const* d_in, const int* in_sizes, int n_in,
                              void* d_out, int out_size, void* d_ws, size_t ws_size,
                              hipStream_t stream) {
    const float* inp = (const float*)d_in[1];
    const int K = in_sizes[1]/6;
    int nv4 = K >> 1;

    const float4* q4 = (const float4*)inp;
    const float4* p4 = (const float4*)(inp + 2*(size_t)K);
    const float4* x4 = (const float4*)(inp + 4*(size_t)K);

    u64* part64  = (u64*)d_ws;                 // [36*NB]
    u64* tslot64 = part64 + 36*NB;             // [NB*12]
    u64* pk64    = tslot64 + NB*12;            // [400]
    float c = 1.0f/(2.0f*(float)K);

    const float* t1i = (const float*)d_in[2];
    const float* b1i = (const float*)d_in[3];
    const float* t2i = (const float*)d_in[4];
    const float* b2i = (const float*)d_in[5];
    const float* invK = (const float*)d_in[6];
    const float* invKb= (const float*)d_in[7];

    float* out = (float*)d_out;
    float4* oq = (float4*)out;
    float4* op = (float4*)(out + 2*(size_t)K);
    float4* ox = (float4*)(out + 4*(size_t)K);

    // zero all epoch-bearing words (epochs restart at 0 every launch)
    size_t zb = (size_t)(36*NB + NB*12 + 400)*sizeof(u64);
    hipMemsetAsync(d_ws, 0, zb, stream);
    k_all<<<dim3(NB), dim3(TPB), 0, stream>>>(q4, p4, x4, nv4,
                                              t1i, b1i, t2i, b2i, invK, invKb,
                                              part64, tslot64, pk64, oq, op, ox, c);
}